// Round 1
// baseline (1154.471 us; speedup 1.0000x reference)
//
#include <hip/hip_runtime.h>
#include <hip/hip_bf16.h>
#include <math.h>

#define NPIX   16384
#define BATCH  8
#define CIN    128
#define HDIM   128
#define WDIM   128
#define BN_EPS 1e-5f
#define EPS_V  1e-6f

// ---- workspace layout (float offsets) ----
#define OFF_K     ((size_t)0)          // 8*16*N     = 2097152
#define OFF_W1F   ((size_t)2097152)    // 128*32     = 4096
#define OFF_W24T  ((size_t)2101248)    // 3*128*9*32 = 110592
#define OFF_WKT   ((size_t)2211840)    // 128*16     = 2048
#define OFF_WVT   ((size_t)2213888)    // 128*128    = 16384
#define OFF_BF    ((size_t)2230272)    // 4*32       = 128
#define OFF_PART  ((size_t)2230400)    // 512*2192   = 1122304
#define OFF_STATS ((size_t)3352704)    // 8*2192     = 17536
// total = 3370240 floats ~= 12.9 MiB

// ---------------- prep: fold BN into weights, transpose to [c][..][o] ----------------
__global__ void prep_kernel(const float* __restrict__ w1, const float* __restrict__ w2,
                            const float* __restrict__ w3, const float* __restrict__ w4,
                            const float* __restrict__ bns, const float* __restrict__ bnb,
                            const float* __restrict__ bnm, const float* __restrict__ bnv,
                            const float* __restrict__ wk, const float* __restrict__ wv,
                            float* __restrict__ ws) {
  float* w1f  = ws + OFF_W1F;
  float* w24t = ws + OFF_W24T;
  float* wkt  = ws + OFF_WKT;
  float* wvt  = ws + OFF_WVT;
  float* bf   = ws + OFF_BF;
  int tid = blockIdx.x * blockDim.x + threadIdx.x;
  int nt  = gridDim.x * blockDim.x;

  for (int i = tid; i < 128; i += nt) {          // bf[br*32+o]
    float inv = bns[i] * rsqrtf(bnv[i] + BN_EPS);
    bf[i] = bnb[i] - bnm[i] * inv;
  }
  for (int i = tid; i < 4096; i += nt) {          // w1f[c][o]
    int c = i >> 5, o = i & 31;
    float inv = bns[o] * rsqrtf(bnv[o] + BN_EPS);  // bn row 0
    w1f[i] = w1[o * 128 + c] * inv;
  }
  for (int i = tid; i < 110592; i += nt) {        // w24t[br][c][k][o]
    int br  = i / 36864;
    int rem = i - br * 36864;
    int c   = rem / 288;
    int k   = (rem % 288) >> 5;
    int o   = rem & 31;
    const float* w = (br == 0) ? w2 : ((br == 1) ? w3 : w4);
    int bo = (br + 1) * 32 + o;
    float inv = bns[bo] * rsqrtf(bnv[bo] + BN_EPS);
    w24t[i] = w[(o * 128 + c) * 9 + k] * inv;
  }
  for (int i = tid; i < 2048; i += nt) {          // wkt[c][m]
    int c = i >> 4, m = i & 15;
    wkt[i] = wk[m * 128 + c];
  }
  for (int i = tid; i < 16384; i += nt) {         // wvt[c][o]
    int c = i >> 7, o = i & 127;
    wvt[i] = wv[o * 128 + c];
  }
}

// ---------------- a1: 1x1 branch (bn+relu) -> out channels [0,32); K -> ws ----------------
__global__ __launch_bounds__(256) void a1_kernel(const float* __restrict__ x,
                                                 const float* __restrict__ ws,
                                                 const float* __restrict__ bk,
                                                 float* __restrict__ out,
                                                 float* __restrict__ Kbuf) {
  __shared__ float lw1[128 * 32];
  __shared__ float lwk[128 * 16];
  __shared__ float lbf[32];
  int t = threadIdx.x;
  const float* w1f = ws + OFF_W1F;
  const float* wkt = ws + OFF_WKT;
  const float* bfp = ws + OFF_BF;
  for (int i = t; i < 4096; i += 256) lw1[i] = w1f[i];
  for (int i = t; i < 2048; i += 256) lwk[i] = wkt[i];
  if (t < 32) lbf[t] = bfp[t];
  __syncthreads();

  int b  = blockIdx.y;
  int px = blockIdx.x * 256 + t;
  const float* xb = x + (size_t)b * 128 * NPIX;

  float acc[48];
#pragma unroll
  for (int i = 0; i < 48; ++i) acc[i] = 0.f;

  for (int c = 0; c < 128; ++c) {
    float xv = xb[(size_t)c * NPIX + px];
    const float4* w1p = (const float4*)(lw1 + c * 32);
#pragma unroll
    for (int j = 0; j < 8; ++j) {
      float4 w = w1p[j];
      acc[j*4+0] = fmaf(w.x, xv, acc[j*4+0]);
      acc[j*4+1] = fmaf(w.y, xv, acc[j*4+1]);
      acc[j*4+2] = fmaf(w.z, xv, acc[j*4+2]);
      acc[j*4+3] = fmaf(w.w, xv, acc[j*4+3]);
    }
    const float4* wkp = (const float4*)(lwk + c * 16);
#pragma unroll
    for (int j = 0; j < 4; ++j) {
      float4 w = wkp[j];
      acc[32+j*4+0] = fmaf(w.x, xv, acc[32+j*4+0]);
      acc[32+j*4+1] = fmaf(w.y, xv, acc[32+j*4+1]);
      acc[32+j*4+2] = fmaf(w.z, xv, acc[32+j*4+2]);
      acc[32+j*4+3] = fmaf(w.w, xv, acc[32+j*4+3]);
    }
  }
#pragma unroll
  for (int o = 0; o < 32; ++o)
    out[((size_t)(b * 128 + o)) * NPIX + px] = fmaxf(acc[o] + lbf[o], 0.f);
#pragma unroll
  for (int m = 0; m < 16; ++m)
    Kbuf[((size_t)(b * 16 + m)) * NPIX + px] = acc[32 + m] + bk[m];
}

// ---------------- a2: dilated 3x3 branches (bn+relu) -> out channels [32,128) ----------------
__global__ __launch_bounds__(256) void a2_kernel(const float* __restrict__ x,
                                                 const float* __restrict__ ws,
                                                 float* __restrict__ out) {
  int t  = threadIdx.x;
  int og = t & 3;          // 4 groups x 8 oc
  int pg = (t >> 2) & 15;  // 16 groups x 8 px
  int r  = t >> 6;         // 4 rows
  int br = blockIdx.z;     // 0..2 -> dil 6/12/18
  int b  = blockIdx.y;
  int h  = blockIdx.x * 4 + r;
  int d  = 6 * (br + 1);

  const float* wt = ws + OFF_W24T + (size_t)br * 36864;  // [c][9][32]
  const float* bf = ws + OFF_BF + (br + 1) * 32;
  const float* xb = x + (size_t)b * 128 * NPIX;
  int w0 = pg << 3;

  float acc[8][8];
#pragma unroll
  for (int p = 0; p < 8; ++p)
#pragma unroll
    for (int o = 0; o < 8; ++o) acc[p][o] = 0.f;

  for (int c = 0; c < 128; ++c) {
    const float* xc = xb + (size_t)c * NPIX;
    const float* wc = wt + c * 288;
#pragma unroll
    for (int kh = 0; kh < 3; ++kh) {
      int row = h + (kh - 1) * d;
      if ((unsigned)row >= 128u) continue;
      const float* xr = xc + row * 128;
#pragma unroll
      for (int kw = 0; kw < 3; ++kw) {
        int wb = w0 + (kw - 1) * d;
        float xv[8];
        if (wb >= 0 && wb <= 120) {
          const float2* p2 = (const float2*)(xr + wb);
#pragma unroll
          for (int j = 0; j < 4; ++j) {
            float2 v = p2[j];
            xv[2*j] = v.x; xv[2*j+1] = v.y;
          }
        } else {
#pragma unroll
          for (int j = 0; j < 8; ++j) {
            int ww = wb + j;
            xv[j] = ((unsigned)ww < 128u) ? xr[ww] : 0.f;
          }
        }
        const float4* wp = (const float4*)(wc + (kh * 3 + kw) * 32 + og * 8);
        float4 wa = wp[0], wbv = wp[1];
        float wr[8] = {wa.x, wa.y, wa.z, wa.w, wbv.x, wbv.y, wbv.z, wbv.w};
#pragma unroll
        for (int p = 0; p < 8; ++p)
#pragma unroll
          for (int o = 0; o < 8; ++o)
            acc[p][o] = fmaf(xv[p], wr[o], acc[p][o]);
      }
    }
  }

  int chbase = (br + 1) * 32 + og * 8;
  int n = h * 128 + w0;
#pragma unroll
  for (int o = 0; o < 8; ++o) {
    float bias = bf[og * 8 + o];
    float* op = out + ((size_t)(b * 128 + chbase + o)) * NPIX + n;
    float4 v0 = make_float4(fmaxf(acc[0][o] + bias, 0.f), fmaxf(acc[1][o] + bias, 0.f),
                            fmaxf(acc[2][o] + bias, 0.f), fmaxf(acc[3][o] + bias, 0.f));
    float4 v1 = make_float4(fmaxf(acc[4][o] + bias, 0.f), fmaxf(acc[5][o] + bias, 0.f),
                            fmaxf(acc[6][o] + bias, 0.f), fmaxf(acc[7][o] + bias, 0.f));
    ((float4*)op)[0] = v0;
    ((float4*)op)[1] = v1;
  }
}

// ---------------- c: V on-the-fly, Kn, accumulate mat/vsum/ksum partials ----------------
__global__ __launch_bounds__(256) void c_kernel(const float* __restrict__ x,
                                                const float* __restrict__ bv,
                                                float* __restrict__ ws) {
  __shared__ float Vl[128 * 129];   // [c][px] stride 129
  __shared__ float knl[16 * 132];   // [m][px] stride 132
  int t   = threadIdx.x;
  int b   = blockIdx.y;
  int blk = blockIdx.x;             // 0..63
  const float* Kb  = ws + OFF_K + (size_t)b * 16 * NPIX;
  const float* xb  = x + (size_t)b * 128 * NPIX;
  const float* wvt = ws + OFF_WVT;

  int m_own = t & 15;
  int c0    = (t >> 4) << 3;   // phase-2 V channel block == phase-3 mat column block
  int pxg   = t & 15;

  float bvr[8];
#pragma unroll
  for (int j = 0; j < 8; ++j) bvr[j] = bv[c0 + j];

  float macc[8] = {0,0,0,0,0,0,0,0};
  float vs[8]   = {0,0,0,0,0,0,0,0};
  float ksum[16];
#pragma unroll
  for (int m = 0; m < 16; ++m) ksum[m] = 0.f;

  for (int tile = blk; tile < 128; tile += 64) {
    __syncthreads();   // previous tile's phase-3 reads done before overwriting LDS
    int pbase = tile << 7;

    // phase 1: Kn for this tile (threads 0..127, one pixel each)
    if (t < 128) {
      float kv[16]; float ss = 0.f;
#pragma unroll
      for (int m = 0; m < 16; ++m) {
        kv[m] = Kb[(size_t)m * NPIX + pbase + t];
        ss = fmaf(kv[m], kv[m], ss);
      }
      float inv = rsqrtf(ss);
#pragma unroll
      for (int m = 0; m < 16; ++m) {
        float kn = kv[m] * inv;
        knl[m * 132 + t] = kn;
        ksum[m] += kn;
      }
    }

    // phase 2: V = wv @ x for this tile (register tile 8c x 8px)
    float v[8][8];
#pragma unroll
    for (int i = 0; i < 8; ++i)
#pragma unroll
      for (int j = 0; j < 8; ++j) v[i][j] = 0.f;
    int px0 = pbase + (pxg << 3);
    for (int k = 0; k < 128; ++k) {
      const float4* xp = (const float4*)(xb + (size_t)k * NPIX + px0);
      float4 xa = xp[0], xc4 = xp[1];
      const float4* wp = (const float4*)(wvt + k * 128 + c0);
      float4 wa = wp[0], wc4 = wp[1];
      float xv[8] = {xa.x, xa.y, xa.z, xa.w, xc4.x, xc4.y, xc4.z, xc4.w};
      float wr[8] = {wa.x, wa.y, wa.z, wa.w, wc4.x, wc4.y, wc4.z, wc4.w};
#pragma unroll
      for (int i = 0; i < 8; ++i)
#pragma unroll
        for (int j = 0; j < 8; ++j)
          v[i][j] = fmaf(wr[i], xv[j], v[i][j]);
    }
#pragma unroll
    for (int i = 0; i < 8; ++i)
#pragma unroll
      for (int j = 0; j < 8; ++j)
        Vl[(c0 + i) * 129 + (pxg << 3) + j] = v[i][j] + bvr[i];
    __syncthreads();

    // phase 3: mat[m][c] += kn[m][px] * V[c][px]; vsum
    for (int px = 0; px < 128; ++px) {
      float knv = knl[m_own * 132 + px];
      float vv[8];
#pragma unroll
      for (int j = 0; j < 8; ++j) vv[j] = Vl[(c0 + j) * 129 + px];
#pragma unroll
      for (int j = 0; j < 8; ++j) macc[j] = fmaf(knv, vv[j], macc[j]);
      if (m_own == 0) {
#pragma unroll
        for (int j = 0; j < 8; ++j) vs[j] += vv[j];
      }
    }
  }

  // write partials
  int blkid = b * 64 + blk;
  float* pp = ws + OFF_PART + (size_t)blkid * 2192;
#pragma unroll
  for (int j = 0; j < 8; ++j) pp[m_own * 128 + c0 + j] = macc[j];
  if (m_own == 0) {
#pragma unroll
    for (int j = 0; j < 8; ++j) pp[2048 + c0 + j] = vs[j];
  }
  __syncthreads();
  if (t < 128) {
#pragma unroll
    for (int m = 0; m < 16; ++m) knl[m * 132 + t] = ksum[m];
  }
  __syncthreads();
  if (t < 16) {
    float s = 0.f;
    for (int i = 0; i < 128; ++i) s += knl[t * 132 + i];
    pp[2048 + 128 + t] = s;
  }
}

// ---------------- reduce partials -> stats ----------------
__global__ void reduce_kernel(float* __restrict__ ws) {
  int b = blockIdx.x, t = threadIdx.x;
  const float* pp = ws + OFF_PART + (size_t)b * 64 * 2192;
  float* st = ws + OFF_STATS + (size_t)b * 2192;
  for (int e = t; e < 2192; e += 256) {
    float s = 0.f;
    for (int g = 0; g < 64; ++g) s += pp[(size_t)g * 2192 + e];
    st[e] = s;
  }
}

// ---------------- d: Q from x_q (in d_out), tailor, final output ----------------
__global__ __launch_bounds__(256) void d_kernel(const float* __restrict__ ws,
                                                const float* __restrict__ wq,
                                                const float* __restrict__ bq,
                                                const float* __restrict__ gamma,
                                                float* __restrict__ out) {
  __shared__ float matl[128 * 16];  // [c][m]
  __shared__ float wql[128 * 16];   // [c][m]
  __shared__ float vsl[128];
  __shared__ float ksl[16];
  int t = threadIdx.x;
  int b = blockIdx.y;
  const float* st = ws + OFF_STATS + (size_t)b * 2192;
  for (int i = t; i < 2048; i += 256) {
    int m = i >> 7, c = i & 127;
    matl[c * 16 + m] = st[i];          // stats mat stored [m][c]
    wql[c * 16 + m]  = wq[m * 128 + c];
  }
  if (t < 128) vsl[t] = st[2048 + t];
  if (t < 16)  ksl[t] = st[2048 + 128 + t] + EPS_V;
  __syncthreads();

  int px = blockIdx.x * 256 + t;
  float* ob = out + (size_t)b * 128 * NPIX;

  float q[16];
#pragma unroll
  for (int m = 0; m < 16; ++m) q[m] = bq[m];
  for (int c = 0; c < 128; ++c) {
    float xv = ob[(size_t)c * NPIX + px];
    const float4* wp = (const float4*)(wql + c * 16);
#pragma unroll
    for (int j = 0; j < 4; ++j) {
      float4 w = wp[j];
      q[j*4+0] = fmaf(w.x, xv, q[j*4+0]);
      q[j*4+1] = fmaf(w.y, xv, q[j*4+1]);
      q[j*4+2] = fmaf(w.z, xv, q[j*4+2]);
      q[j*4+3] = fmaf(w.w, xv, q[j*4+3]);
    }
  }
  float ss = 0.f;
#pragma unroll
  for (int m = 0; m < 16; ++m) ss = fmaf(q[m], q[m], ss);
  float inv = rsqrtf(ss);
#pragma unroll
  for (int m = 0; m < 16; ++m) q[m] *= inv;   // qn
  float den = (float)NPIX;
#pragma unroll
  for (int m = 0; m < 16; ++m) den = fmaf(q[m], ksl[m], den);
  float tl = gamma[0] / den;

  for (int c = 0; c < 128; ++c) {
    float s = vsl[c];
    const float4* mp = (const float4*)(matl + c * 16);
#pragma unroll
    for (int j = 0; j < 4; ++j) {
      float4 w = mp[j];
      s = fmaf(w.x, q[j*4+0], s);
      s = fmaf(w.y, q[j*4+1], s);
      s = fmaf(w.z, q[j*4+2], s);
      s = fmaf(w.w, q[j*4+3], s);
    }
    ob[(size_t)c * NPIX + px] = tl * s;
  }
}

extern "C" void kernel_launch(void* const* d_in, const int* in_sizes, int n_in,
                              void* d_out, int out_size, void* d_ws, size_t ws_size,
                              hipStream_t stream) {
  (void)in_sizes; (void)n_in; (void)out_size; (void)ws_size;
  const float* x   = (const float*)d_in[0];
  const float* w1  = (const float*)d_in[1];
  const float* w2  = (const float*)d_in[2];
  const float* w3  = (const float*)d_in[3];
  const float* w4  = (const float*)d_in[4];
  const float* bns = (const float*)d_in[5];
  const float* bnb = (const float*)d_in[6];
  const float* bnm = (const float*)d_in[7];
  const float* bnv = (const float*)d_in[8];
  const float* wq  = (const float*)d_in[9];
  const float* bq  = (const float*)d_in[10];
  const float* wk  = (const float*)d_in[11];
  const float* bk  = (const float*)d_in[12];
  const float* wv  = (const float*)d_in[13];
  const float* bv  = (const float*)d_in[14];
  const float* gm  = (const float*)d_in[15];
  float* ws  = (float*)d_ws;
  float* out = (float*)d_out;

  prep_kernel<<<64, 256, 0, stream>>>(w1, w2, w3, w4, bns, bnb, bnm, bnv, wk, wv, ws);
  a1_kernel<<<dim3(64, 8), 256, 0, stream>>>(x, ws, bk, out, ws + OFF_K);
  a2_kernel<<<dim3(32, 8, 3), 256, 0, stream>>>(x, ws, out);
  c_kernel<<<dim3(64, 8), 256, 0, stream>>>(x, bv, ws);
  reduce_kernel<<<8, 256, 0, stream>>>(ws);
  d_kernel<<<dim3(64, 8), 256, 0, stream>>>(ws, wq, bq, gm, out);
}

// Round 2
// 359.163 us; speedup vs baseline: 3.2143x; 3.2143x over previous
//
#include <hip/hip_runtime.h>
#include <hip/hip_bf16.h>
#include <math.h>

#define NPIX   16384
#define BATCH  8
#define BN_EPS 1e-5f
#define EPS_V  1e-6f

typedef __attribute__((ext_vector_type(8))) short bf16x8;
typedef __attribute__((ext_vector_type(4))) float f32x4;

// ---- workspace layout (float offsets) ----
// common
#define OFF_K     ((size_t)0)          // 8*16*N   = 2097152
#define OFF_W1F   ((size_t)2097152)    // 128*32   = 4096
#define OFF_WKT   ((size_t)2101248)    // 128*16   = 2048
#define OFF_WVT   ((size_t)2103296)    // 128*128  = 16384
#define OFF_BF    ((size_t)2119680)    // 4*32     = 128
#define OFF_PART  ((size_t)2119808)    // 512*2192 = 1122304
#define OFF_STATS ((size_t)3242112)    // 8*2192   = 17536
#define BASE_END  ((size_t)3259648)
// new (bf16-MFMA) path extras
#define OFF_WBT   BASE_END             // 3*9*32*128 ushort = 55296 floats
#define OFF_ZB    ((size_t)3314944)    // 32 floats (zero page)
#define OFF_XT    ((size_t)3314976)    // 8*16384*128 ushort = 8388608 floats
#define NEW_END   ((size_t)11703584)
// old (fp32) fallback extras
#define OFF_W24T  BASE_END             // 3*128*9*32 = 110592
#define OLD_END   ((size_t)3370240)

__device__ inline unsigned short f2bf(float f) {
  union { float f; unsigned int u; } v; v.f = f;
  unsigned int r = (v.u + 0x7FFFu + ((v.u >> 16) & 1u)) >> 16;
  return (unsigned short)r;
}

// ---------------- prep_common: BN-folded 1x1 weights, K/V weights, biases ----------------
__global__ void prep_common_kernel(const float* __restrict__ w1,
                                   const float* __restrict__ bns, const float* __restrict__ bnb,
                                   const float* __restrict__ bnm, const float* __restrict__ bnv,
                                   const float* __restrict__ wk, const float* __restrict__ wv,
                                   float* __restrict__ w1f, float* __restrict__ wkt,
                                   float* __restrict__ wvt, float* __restrict__ bf) {
  int tid = blockIdx.x * blockDim.x + threadIdx.x;
  int nt  = gridDim.x * blockDim.x;
  for (int i = tid; i < 128; i += nt) {
    float inv = bns[i] * rsqrtf(bnv[i] + BN_EPS);
    bf[i] = bnb[i] - bnm[i] * inv;
  }
  for (int i = tid; i < 4096; i += nt) {          // w1f[c][o]
    int c = i >> 5, o = i & 31;
    float inv = bns[o] * rsqrtf(bnv[o] + BN_EPS);
    w1f[i] = w1[o * 128 + c] * inv;
  }
  for (int i = tid; i < 2048; i += nt) {          // wkt[c][m]
    int c = i >> 4, m = i & 15;
    wkt[i] = wk[m * 128 + c];
  }
  for (int i = tid; i < 16384; i += nt) {         // wvt[c][o]
    int c = i >> 7, o = i & 127;
    wvt[i] = wv[o * 128 + c];
  }
}

// ---------------- prep_convb: bf16 conv weights [br][tap][oc][c] + zero page ----------------
__global__ void prep_convb_kernel(const float* __restrict__ w2, const float* __restrict__ w3,
                                  const float* __restrict__ w4,
                                  const float* __restrict__ bns, const float* __restrict__ bnv,
                                  unsigned short* __restrict__ wbt, float* __restrict__ zb) {
  int tid = blockIdx.x * blockDim.x + threadIdx.x;
  int nt  = gridDim.x * blockDim.x;
  if (tid < 32) zb[tid] = 0.f;
  for (int i = tid; i < 110592; i += nt) {
    int br   = i / 36864;
    int rem  = i - br * 36864;
    int tap  = rem >> 12;            // /4096
    int rem2 = rem & 4095;
    int o    = rem2 >> 7;
    int c    = rem2 & 127;
    const float* w = (br == 0) ? w2 : ((br == 1) ? w3 : w4);
    int bo = (br + 1) * 32 + o;
    float inv = bns[bo] * rsqrtf(bnv[bo] + BN_EPS);
    wbt[i] = f2bf(w[(o * 128 + c) * 9 + tap] * inv);
  }
}

// ---------------- prep_convf: fp32 conv weights (fallback) [br][c][tap][o] ----------------
__global__ void prep_convf_kernel(const float* __restrict__ w2, const float* __restrict__ w3,
                                  const float* __restrict__ w4,
                                  const float* __restrict__ bns, const float* __restrict__ bnv,
                                  float* __restrict__ w24t) {
  int tid = blockIdx.x * blockDim.x + threadIdx.x;
  int nt  = gridDim.x * blockDim.x;
  for (int i = tid; i < 110592; i += nt) {
    int br  = i / 36864;
    int rem = i - br * 36864;
    int c   = rem / 288;
    int k   = (rem % 288) >> 5;
    int o   = rem & 31;
    const float* w = (br == 0) ? w2 : ((br == 1) ? w3 : w4);
    int bo = (br + 1) * 32 + o;
    float inv = bns[bo] * rsqrtf(bnv[bo] + BN_EPS);
    w24t[i] = w[(o * 128 + c) * 9 + k] * inv;
  }
}

// ---------------- a0: transpose x -> xt bf16 [b][px][c] ----------------
__global__ __launch_bounds__(256) void a0_kernel(const float* __restrict__ x,
                                                 unsigned short* __restrict__ xt) {
  __shared__ unsigned short Ts[64][132];
  int t   = threadIdx.x;
  int b   = blockIdx.y;
  int px0 = blockIdx.x * 64;
  const float* xb = x + (size_t)b * 128 * NPIX;
  int p = t & 63, cq = t >> 6;
#pragma unroll 8
  for (int i = 0; i < 32; ++i) {
    int c = cq * 32 + i;
    Ts[p][c] = f2bf(xb[(size_t)c * NPIX + px0 + p]);
  }
  __syncthreads();
  int pw = t >> 2, cg = t & 3;
  unsigned short* dst = xt + ((size_t)b * NPIX + px0 + pw) * 128 + cg * 32;
#pragma unroll
  for (int k = 0; k < 8; ++k) {
    uint2 v = *(const uint2*)(&Ts[pw][cg * 32 + k * 4]);
    *(uint2*)(dst + k * 4) = v;
  }
}

// ---------------- a1: 1x1 branch (bn+relu) -> out channels [0,32); K -> ws ----------------
__global__ __launch_bounds__(256) void a1_kernel(const float* __restrict__ x,
                                                 const float* __restrict__ w1f,
                                                 const float* __restrict__ wkt,
                                                 const float* __restrict__ bfp,
                                                 const float* __restrict__ bk,
                                                 float* __restrict__ out,
                                                 float* __restrict__ Kbuf) {
  __shared__ float lw1[128 * 32];
  __shared__ float lwk[128 * 16];
  __shared__ float lbf[32];
  int t = threadIdx.x;
  for (int i = t; i < 4096; i += 256) lw1[i] = w1f[i];
  for (int i = t; i < 2048; i += 256) lwk[i] = wkt[i];
  if (t < 32) lbf[t] = bfp[t];
  __syncthreads();

  int b  = blockIdx.y;
  int px = blockIdx.x * 256 + t;
  const float* xb = x + (size_t)b * 128 * NPIX;

  float acc[48];
#pragma unroll
  for (int i = 0; i < 48; ++i) acc[i] = 0.f;

  for (int c = 0; c < 128; ++c) {
    float xv = xb[(size_t)c * NPIX + px];
    const float4* w1p = (const float4*)(lw1 + c * 32);
#pragma unroll
    for (int j = 0; j < 8; ++j) {
      float4 w = w1p[j];
      acc[j*4+0] = fmaf(w.x, xv, acc[j*4+0]);
      acc[j*4+1] = fmaf(w.y, xv, acc[j*4+1]);
      acc[j*4+2] = fmaf(w.z, xv, acc[j*4+2]);
      acc[j*4+3] = fmaf(w.w, xv, acc[j*4+3]);
    }
    const float4* wkp = (const float4*)(lwk + c * 16);
#pragma unroll
    for (int j = 0; j < 4; ++j) {
      float4 w = wkp[j];
      acc[32+j*4+0] = fmaf(w.x, xv, acc[32+j*4+0]);
      acc[32+j*4+1] = fmaf(w.y, xv, acc[32+j*4+1]);
      acc[32+j*4+2] = fmaf(w.z, xv, acc[32+j*4+2]);
      acc[32+j*4+3] = fmaf(w.w, xv, acc[32+j*4+3]);
    }
  }
#pragma unroll
  for (int o = 0; o < 32; ++o)
    out[((size_t)(b * 128 + o)) * NPIX + px] = fmaxf(acc[o] + lbf[o], 0.f);
#pragma unroll
  for (int m = 0; m < 16; ++m)
    Kbuf[((size_t)(b * 16 + m)) * NPIX + px] = acc[32 + m] + bk[m];
}

// ---------------- a2m: dilated 3x3 branches via bf16 MFMA ----------------
// out[32oc x 256px] per block; A = W[oc][c], B = xt[px][c] both with c contiguous.
__global__ __launch_bounds__(256) void a2m_kernel(const unsigned short* __restrict__ xt,
                                                  const unsigned short* __restrict__ wbt,
                                                  const float* __restrict__ bfp,
                                                  const unsigned short* __restrict__ zb,
                                                  float* __restrict__ out) {
  int t    = threadIdx.x;
  int wave = t >> 6, lane = t & 63;
  int l15  = lane & 15, cg = lane >> 4;
  int br   = blockIdx.z, b = blockIdx.y;
  int d    = 6 * (br + 1);
  int h    = blockIdx.x * 2 + (wave >> 1);
  int n0   = (wave & 1) * 64;
  const unsigned short* xb = xt + (size_t)b * NPIX * 128;
  const unsigned short* wb = wbt + (size_t)br * 9 * 32 * 128;

  f32x4 acc[2][4];
#pragma unroll
  for (int i = 0; i < 2; ++i)
#pragma unroll
    for (int j = 0; j < 4; ++j) acc[i][j] = (f32x4){0.f, 0.f, 0.f, 0.f};

  for (int cc = 0; cc < 4; ++cc) {
    int c0 = cc * 32 + cg * 8;
#pragma unroll
    for (int kh = 0; kh < 3; ++kh) {
      int srow = h + (kh - 1) * d;
      if ((unsigned)srow >= 128u) continue;          // wave-uniform skip
      const unsigned short* xr = xb + ((size_t)srow * 128) * 128 + c0;
#pragma unroll
      for (int kw = 0; kw < 3; ++kw) {
        int tap = kh * 3 + kw;
        const unsigned short* wt = wb + (size_t)(tap * 32) * 128 + c0;
        bf16x8 a0 = *(const bf16x8*)(wt + (size_t)l15 * 128);
        bf16x8 a1 = *(const bf16x8*)(wt + (size_t)(l15 + 16) * 128);
        int colbase = n0 + l15 + (kw - 1) * d;
#pragma unroll
        for (int nf = 0; nf < 4; ++nf) {
          int col = colbase + nf * 16;
          const unsigned short* sp =
              ((unsigned)col < 128u) ? (xr + (size_t)col * 128) : zb;
          bf16x8 bv = *(const bf16x8*)sp;
          acc[0][nf] = __builtin_amdgcn_mfma_f32_16x16x32_bf16(a0, bv, acc[0][nf], 0, 0, 0);
          acc[1][nf] = __builtin_amdgcn_mfma_f32_16x16x32_bf16(a1, bv, acc[1][nf], 0, 0, 0);
        }
      }
    }
  }

  int ocb = (br + 1) * 32;
  int pxw = blockIdx.x * 256 + (wave >> 1) * 128 + n0;
#pragma unroll
  for (int mf = 0; mf < 2; ++mf) {
#pragma unroll
    for (int r = 0; r < 4; ++r) {
      int oc = mf * 16 + cg * 4 + r;
      float bias = bfp[ocb + oc];
      float* op = out + ((size_t)(b * 128 + ocb + oc)) * NPIX + pxw + l15;
#pragma unroll
      for (int nf = 0; nf < 4; ++nf)
        op[nf * 16] = fmaxf(acc[mf][nf][r] + bias, 0.f);
    }
  }
}

// ---------------- a2f: fp32 fallback dilated conv ----------------
__global__ __launch_bounds__(256) void a2f_kernel(const float* __restrict__ x,
                                                  const float* __restrict__ w24t,
                                                  const float* __restrict__ bfp,
                                                  float* __restrict__ out) {
  int t  = threadIdx.x;
  int og = t & 3;
  int pg = (t >> 2) & 15;
  int r  = t >> 6;
  int br = blockIdx.z;
  int b  = blockIdx.y;
  int h  = blockIdx.x * 4 + r;
  int d  = 6 * (br + 1);

  const float* wt = w24t + (size_t)br * 36864;
  const float* bf = bfp + (br + 1) * 32;
  const float* xb = x + (size_t)b * 128 * NPIX;
  int w0 = pg << 3;

  float acc[8][8];
#pragma unroll
  for (int p = 0; p < 8; ++p)
#pragma unroll
    for (int o = 0; o < 8; ++o) acc[p][o] = 0.f;

  for (int c = 0; c < 128; ++c) {
    const float* xc = xb + (size_t)c * NPIX;
    const float* wc = wt + c * 288;
#pragma unroll
    for (int kh = 0; kh < 3; ++kh) {
      int row = h + (kh - 1) * d;
      if ((unsigned)row >= 128u) continue;
      const float* xr = xc + row * 128;
#pragma unroll
      for (int kw = 0; kw < 3; ++kw) {
        int wb = w0 + (kw - 1) * d;
        float xv[8];
        if (wb >= 0 && wb <= 120) {
          const float2* p2 = (const float2*)(xr + wb);
#pragma unroll
          for (int j = 0; j < 4; ++j) {
            float2 v = p2[j];
            xv[2*j] = v.x; xv[2*j+1] = v.y;
          }
        } else {
#pragma unroll
          for (int j = 0; j < 8; ++j) {
            int ww = wb + j;
            xv[j] = ((unsigned)ww < 128u) ? xr[ww] : 0.f;
          }
        }
        const float4* wp = (const float4*)(wc + (kh * 3 + kw) * 32 + og * 8);
        float4 wa = wp[0], wbv = wp[1];
        float wr[8] = {wa.x, wa.y, wa.z, wa.w, wbv.x, wbv.y, wbv.z, wbv.w};
#pragma unroll
        for (int p = 0; p < 8; ++p)
#pragma unroll
          for (int o = 0; o < 8; ++o)
            acc[p][o] = fmaf(xv[p], wr[o], acc[p][o]);
      }
    }
  }

  int chbase = (br + 1) * 32 + og * 8;
  int n = h * 128 + w0;
#pragma unroll
  for (int o = 0; o < 8; ++o) {
    float bias = bf[og * 8 + o];
    float* op = out + ((size_t)(b * 128 + chbase + o)) * NPIX + n;
    float4 v0 = make_float4(fmaxf(acc[0][o] + bias, 0.f), fmaxf(acc[1][o] + bias, 0.f),
                            fmaxf(acc[2][o] + bias, 0.f), fmaxf(acc[3][o] + bias, 0.f));
    float4 v1 = make_float4(fmaxf(acc[4][o] + bias, 0.f), fmaxf(acc[5][o] + bias, 0.f),
                            fmaxf(acc[6][o] + bias, 0.f), fmaxf(acc[7][o] + bias, 0.f));
    ((float4*)op)[0] = v0;
    ((float4*)op)[1] = v1;
  }
}

// ---------------- c: V on-the-fly, Kn, accumulate mat/vsum/ksum partials ----------------
__global__ __launch_bounds__(256) void c_kernel(const float* __restrict__ x,
                                                const float* __restrict__ bv,
                                                const float* __restrict__ Kbuf,
                                                const float* __restrict__ wvt,
                                                float* __restrict__ part) {
  __shared__ float Vl[128 * 129];
  __shared__ float knl[16 * 132];
  int t   = threadIdx.x;
  int b   = blockIdx.y;
  int blk = blockIdx.x;
  const float* Kb = Kbuf + (size_t)b * 16 * NPIX;
  const float* xb = x + (size_t)b * 128 * NPIX;

  int m_own = t & 15;
  int c0    = (t >> 4) << 3;
  int pxg   = t & 15;

  float bvr[8];
#pragma unroll
  for (int j = 0; j < 8; ++j) bvr[j] = bv[c0 + j];

  float macc[8] = {0,0,0,0,0,0,0,0};
  float vs[8]   = {0,0,0,0,0,0,0,0};
  float ksum[16];
#pragma unroll
  for (int m = 0; m < 16; ++m) ksum[m] = 0.f;

  for (int tile = blk; tile < 128; tile += 64) {
    __syncthreads();
    int pbase = tile << 7;

    if (t < 128) {
      float kv[16]; float ss = 0.f;
#pragma unroll
      for (int m = 0; m < 16; ++m) {
        kv[m] = Kb[(size_t)m * NPIX + pbase + t];
        ss = fmaf(kv[m], kv[m], ss);
      }
      float inv = rsqrtf(ss);
#pragma unroll
      for (int m = 0; m < 16; ++m) {
        float kn = kv[m] * inv;
        knl[m * 132 + t] = kn;
        ksum[m] += kn;
      }
    }

    float v[8][8];
#pragma unroll
    for (int i = 0; i < 8; ++i)
#pragma unroll
      for (int j = 0; j < 8; ++j) v[i][j] = 0.f;
    int px0 = pbase + (pxg << 3);
    for (int k = 0; k < 128; ++k) {
      const float4* xp = (const float4*)(xb + (size_t)k * NPIX + px0);
      float4 xa = xp[0], xc4 = xp[1];
      const float4* wp = (const float4*)(wvt + k * 128 + c0);
      float4 wa = wp[0], wc4 = wp[1];
      float xv[8] = {xa.x, xa.y, xa.z, xa.w, xc4.x, xc4.y, xc4.z, xc4.w};
      float wr[8] = {wa.x, wa.y, wa.z, wa.w, wc4.x, wc4.y, wc4.z, wc4.w};
#pragma unroll
      for (int i = 0; i < 8; ++i)
#pragma unroll
        for (int j = 0; j < 8; ++j)
          v[i][j] = fmaf(wr[i], xv[j], v[i][j]);
    }
#pragma unroll
    for (int i = 0; i < 8; ++i)
#pragma unroll
      for (int j = 0; j < 8; ++j)
        Vl[(c0 + i) * 129 + (pxg << 3) + j] = v[i][j] + bvr[i];
    __syncthreads();

    for (int px = 0; px < 128; ++px) {
      float knv = knl[m_own * 132 + px];
      float vv[8];
#pragma unroll
      for (int j = 0; j < 8; ++j) vv[j] = Vl[(c0 + j) * 129 + px];
#pragma unroll
      for (int j = 0; j < 8; ++j) macc[j] = fmaf(knv, vv[j], macc[j]);
      if (m_own == 0) {
#pragma unroll
        for (int j = 0; j < 8; ++j) vs[j] += vv[j];
      }
    }
  }

  int blkid = b * 64 + blk;
  float* pp = part + (size_t)blkid * 2192;
#pragma unroll
  for (int j = 0; j < 8; ++j) pp[m_own * 128 + c0 + j] = macc[j];
  if (m_own == 0) {
#pragma unroll
    for (int j = 0; j < 8; ++j) pp[2048 + c0 + j] = vs[j];
  }
  __syncthreads();
  if (t < 128) {
#pragma unroll
    for (int m = 0; m < 16; ++m) knl[m * 132 + t] = ksum[m];
  }
  __syncthreads();
  if (t < 16) {
    float s = 0.f;
    for (int i = 0; i < 128; ++i) s += knl[t * 132 + i];
    pp[2048 + 128 + t] = s;
  }
}

// ---------------- reduce partials -> stats ----------------
__global__ void reduce_kernel(const float* __restrict__ part, float* __restrict__ stats) {
  int b = blockIdx.x, t = threadIdx.x;
  const float* pp = part + (size_t)b * 64 * 2192;
  float* st = stats + (size_t)b * 2192;
  for (int e = t; e < 2192; e += 256) {
    float s = 0.f;
    for (int g = 0; g < 64; ++g) s += pp[(size_t)g * 2192 + e];
    st[e] = s;
  }
}

// ---------------- d: Q from x_q (in d_out), tailor, final output ----------------
__global__ __launch_bounds__(256) void d_kernel(const float* __restrict__ stats,
                                                const float* __restrict__ wq,
                                                const float* __restrict__ bq,
                                                const float* __restrict__ gamma,
                                                float* __restrict__ out) {
  __shared__ float matl[128 * 16];
  __shared__ float wql[128 * 16];
  __shared__ float vsl[128];
  __shared__ float ksl[16];
  int t = threadIdx.x;
  int b = blockIdx.y;
  const float* st = stats + (size_t)b * 2192;
  for (int i = t; i < 2048; i += 256) {
    int m = i >> 7, c = i & 127;
    matl[c * 16 + m] = st[i];
    wql[c * 16 + m]  = wq[m * 128 + c];
  }
  if (t < 128) vsl[t] = st[2048 + t];
  if (t < 16)  ksl[t] = st[2048 + 128 + t] + EPS_V;
  __syncthreads();

  int px = blockIdx.x * 256 + t;
  float* ob = out + (size_t)b * 128 * NPIX;

  float q[16];
#pragma unroll
  for (int m = 0; m < 16; ++m) q[m] = bq[m];
  for (int c = 0; c < 128; ++c) {
    float xv = ob[(size_t)c * NPIX + px];
    const float4* wp = (const float4*)(wql + c * 16);
#pragma unroll
    for (int j = 0; j < 4; ++j) {
      float4 w = wp[j];
      q[j*4+0] = fmaf(w.x, xv, q[j*4+0]);
      q[j*4+1] = fmaf(w.y, xv, q[j*4+1]);
      q[j*4+2] = fmaf(w.z, xv, q[j*4+2]);
      q[j*4+3] = fmaf(w.w, xv, q[j*4+3]);
    }
  }
  float ss = 0.f;
#pragma unroll
  for (int m = 0; m < 16; ++m) ss = fmaf(q[m], q[m], ss);
  float inv = rsqrtf(ss);
#pragma unroll
  for (int m = 0; m < 16; ++m) q[m] *= inv;
  float den = (float)NPIX;
#pragma unroll
  for (int m = 0; m < 16; ++m) den = fmaf(q[m], ksl[m], den);
  float tl = gamma[0] / den;

  for (int c = 0; c < 128; ++c) {
    float s = vsl[c];
    const float4* mp = (const float4*)(matl + c * 16);
#pragma unroll
    for (int j = 0; j < 4; ++j) {
      float4 w = mp[j];
      s = fmaf(w.x, q[j*4+0], s);
      s = fmaf(w.y, q[j*4+1], s);
      s = fmaf(w.z, q[j*4+2], s);
      s = fmaf(w.w, q[j*4+3], s);
    }
    ob[(size_t)c * NPIX + px] = tl * s;
  }
}

extern "C" void kernel_launch(void* const* d_in, const int* in_sizes, int n_in,
                              void* d_out, int out_size, void* d_ws, size_t ws_size,
                              hipStream_t stream) {
  (void)in_sizes; (void)n_in; (void)out_size;
  const float* x   = (const float*)d_in[0];
  const float* w1  = (const float*)d_in[1];
  const float* w2  = (const float*)d_in[2];
  const float* w3  = (const float*)d_in[3];
  const float* w4  = (const float*)d_in[4];
  const float* bns = (const float*)d_in[5];
  const float* bnb = (const float*)d_in[6];
  const float* bnm = (const float*)d_in[7];
  const float* bnv = (const float*)d_in[8];
  const float* wq  = (const float*)d_in[9];
  const float* bq  = (const float*)d_in[10];
  const float* wk  = (const float*)d_in[11];
  const float* bk  = (const float*)d_in[12];
  const float* wv  = (const float*)d_in[13];
  const float* bv  = (const float*)d_in[14];
  const float* gm  = (const float*)d_in[15];
  float* ws  = (float*)d_ws;
  float* out = (float*)d_out;

  float* Kbuf = ws + OFF_K;
  float* w1f  = ws + OFF_W1F;
  float* wkt  = ws + OFF_WKT;
  float* wvt  = ws + OFF_WVT;
  float* bfp  = ws + OFF_BF;
  float* part = ws + OFF_PART;
  float* stat = ws + OFF_STATS;

  prep_common_kernel<<<64, 256, 0, stream>>>(w1, bns, bnb, bnm, bnv, wk, wv,
                                             w1f, wkt, wvt, bfp);

  bool use_mfma = ws_size >= NEW_END * sizeof(float);
  if (use_mfma) {
    unsigned short* wbt = (unsigned short*)(ws + OFF_WBT);
    float*          zb  = ws + OFF_ZB;
    unsigned short* xt  = (unsigned short*)(ws + OFF_XT);
    prep_convb_kernel<<<64, 256, 0, stream>>>(w2, w3, w4, bns, bnv, wbt, zb);
    a0_kernel<<<dim3(256, 8), 256, 0, stream>>>(x, xt);
    a1_kernel<<<dim3(64, 8), 256, 0, stream>>>(x, w1f, wkt, bfp, bk, out, Kbuf);
    a2m_kernel<<<dim3(64, 8, 3), 256, 0, stream>>>(xt, wbt, bfp,
                                                   (const unsigned short*)zb, out);
  } else {
    float* w24t = ws + OFF_W24T;
    prep_convf_kernel<<<64, 256, 0, stream>>>(w2, w3, w4, bns, bnv, w24t);
    a1_kernel<<<dim3(64, 8), 256, 0, stream>>>(x, w1f, wkt, bfp, bk, out, Kbuf);
    a2f_kernel<<<dim3(32, 8, 3), 256, 0, stream>>>(x, w24t, bfp, out);
  }
  c_kernel<<<dim3(64, 8), 256, 0, stream>>>(x, bv, Kbuf, wvt, part);
  reduce_kernel<<<8, 256, 0, stream>>>(part, stat);
  d_kernel<<<dim3(64, 8), 256, 0, stream>>>(stat, wq, bq, gm, out);
}

// Round 3
// 311.380 us; speedup vs baseline: 3.7076x; 1.1535x over previous
//
#include <hip/hip_runtime.h>
#include <hip/hip_bf16.h>
#include <math.h>

#define NPIX   16384
#define BATCH  8
#define BN_EPS 1e-5f
#define EPS_V  1e-6f

typedef __attribute__((ext_vector_type(8))) short bf16x8;
typedef __attribute__((ext_vector_type(4))) float f32x4;

// ---- workspace layout (float offsets) ----
// common
#define OFF_K     ((size_t)0)          // 8*16*N   = 2097152
#define OFF_W1F   ((size_t)2097152)    // 128*32   = 4096
#define OFF_WKT   ((size_t)2101248)    // 128*16   = 2048
#define OFF_WVT   ((size_t)2103296)    // 128*128  = 16384
#define OFF_BF    ((size_t)2119680)    // 4*32     = 128
#define OFF_PART  ((size_t)2119808)    // 512*2192 = 1122304
#define OFF_STATS ((size_t)3242112)    // 8*2192   = 17536
#define BASE_END  ((size_t)3259648)
// new (bf16-MFMA) path extras
#define OFF_WBT   BASE_END             // 3*9*32*128 ushort = 55296 floats
#define OFF_ZB    ((size_t)3314944)    // 32 floats (zero page)
#define OFF_XT    ((size_t)3314976)    // 8*16384*128 ushort = 8388608 floats
#define OFF_WVB   ((size_t)11703584)   // 128*128 ushort = 8192 floats
#define NEW_END   ((size_t)11711776)
// old (fp32) fallback extras
#define OFF_W24T  BASE_END             // 3*128*9*32 = 110592
#define OLD_END   ((size_t)3370240)

__device__ inline unsigned short f2bf(float f) {
  union { float f; unsigned int u; } v; v.f = f;
  unsigned int r = (v.u + 0x7FFFu + ((v.u >> 16) & 1u)) >> 16;
  return (unsigned short)r;
}

// ---------------- prep_common: BN-folded 1x1 weights, K/V weights, biases ----------------
__global__ void prep_common_kernel(const float* __restrict__ w1,
                                   const float* __restrict__ bns, const float* __restrict__ bnb,
                                   const float* __restrict__ bnm, const float* __restrict__ bnv,
                                   const float* __restrict__ wk, const float* __restrict__ wv,
                                   float* __restrict__ w1f, float* __restrict__ wkt,
                                   float* __restrict__ wvt, float* __restrict__ bf) {
  int tid = blockIdx.x * blockDim.x + threadIdx.x;
  int nt  = gridDim.x * blockDim.x;
  for (int i = tid; i < 128; i += nt) {
    float inv = bns[i] * rsqrtf(bnv[i] + BN_EPS);
    bf[i] = bnb[i] - bnm[i] * inv;
  }
  for (int i = tid; i < 4096; i += nt) {          // w1f[c][o]
    int c = i >> 5, o = i & 31;
    float inv = bns[o] * rsqrtf(bnv[o] + BN_EPS);
    w1f[i] = w1[o * 128 + c] * inv;
  }
  for (int i = tid; i < 2048; i += nt) {          // wkt[c][m]
    int c = i >> 4, m = i & 15;
    wkt[i] = wk[m * 128 + c];
  }
  for (int i = tid; i < 16384; i += nt) {         // wvt[c][o]
    int c = i >> 7, o = i & 127;
    wvt[i] = wv[o * 128 + c];
  }
}

// ---------------- prep_convb: bf16 conv weights [br][tap][oc][c], bf16 wv, zero page ----------------
__global__ void prep_convb_kernel(const float* __restrict__ w2, const float* __restrict__ w3,
                                  const float* __restrict__ w4,
                                  const float* __restrict__ bns, const float* __restrict__ bnv,
                                  const float* __restrict__ wv,
                                  unsigned short* __restrict__ wbt, float* __restrict__ zb,
                                  unsigned short* __restrict__ wvb) {
  int tid = blockIdx.x * blockDim.x + threadIdx.x;
  int nt  = gridDim.x * blockDim.x;
  if (tid < 32) zb[tid] = 0.f;
  for (int i = tid; i < 16384; i += nt)           // wvb[oc][c] (same layout as wv)
    wvb[i] = f2bf(wv[i]);
  for (int i = tid; i < 110592; i += nt) {
    int br   = i / 36864;
    int rem  = i - br * 36864;
    int tap  = rem >> 12;            // /4096
    int rem2 = rem & 4095;
    int o    = rem2 >> 7;
    int c    = rem2 & 127;
    const float* w = (br == 0) ? w2 : ((br == 1) ? w3 : w4);
    int bo = (br + 1) * 32 + o;
    float inv = bns[bo] * rsqrtf(bnv[bo] + BN_EPS);
    wbt[i] = f2bf(w[(o * 128 + c) * 9 + tap] * inv);
  }
}

// ---------------- prep_convf: fp32 conv weights (fallback) [br][c][tap][o] ----------------
__global__ void prep_convf_kernel(const float* __restrict__ w2, const float* __restrict__ w3,
                                  const float* __restrict__ w4,
                                  const float* __restrict__ bns, const float* __restrict__ bnv,
                                  float* __restrict__ w24t) {
  int tid = blockIdx.x * blockDim.x + threadIdx.x;
  int nt  = gridDim.x * blockDim.x;
  for (int i = tid; i < 110592; i += nt) {
    int br  = i / 36864;
    int rem = i - br * 36864;
    int c   = rem / 288;
    int k   = (rem % 288) >> 5;
    int o   = rem & 31;
    const float* w = (br == 0) ? w2 : ((br == 1) ? w3 : w4);
    int bo = (br + 1) * 32 + o;
    float inv = bns[bo] * rsqrtf(bnv[bo] + BN_EPS);
    w24t[i] = w[(o * 128 + c) * 9 + k] * inv;
  }
}

// ---------------- a0: transpose x -> xt bf16 [b][px][c] ----------------
__global__ __launch_bounds__(256) void a0_kernel(const float* __restrict__ x,
                                                 unsigned short* __restrict__ xt) {
  __shared__ unsigned short Ts[64][132];
  int t   = threadIdx.x;
  int b   = blockIdx.y;
  int px0 = blockIdx.x * 64;
  const float* xb = x + (size_t)b * 128 * NPIX;
  int p = t & 63, cq = t >> 6;
#pragma unroll 8
  for (int i = 0; i < 32; ++i) {
    int c = cq * 32 + i;
    Ts[p][c] = f2bf(xb[(size_t)c * NPIX + px0 + p]);
  }
  __syncthreads();
  int pw = t >> 2, cg = t & 3;
  unsigned short* dst = xt + ((size_t)b * NPIX + px0 + pw) * 128 + cg * 32;
#pragma unroll
  for (int k = 0; k < 8; ++k) {
    uint2 v = *(const uint2*)(&Ts[pw][cg * 32 + k * 4]);
    *(uint2*)(dst + k * 4) = v;
  }
}

// ---------------- a1: 1x1 branch (bn+relu) -> out channels [0,32); K -> ws ----------------
__global__ __launch_bounds__(256) void a1_kernel(const float* __restrict__ x,
                                                 const float* __restrict__ w1f,
                                                 const float* __restrict__ wkt,
                                                 const float* __restrict__ bfp,
                                                 const float* __restrict__ bk,
                                                 float* __restrict__ out,
                                                 float* __restrict__ Kbuf) {
  __shared__ float lw1[128 * 32];
  __shared__ float lwk[128 * 16];
  __shared__ float lbf[32];
  int t = threadIdx.x;
  for (int i = t; i < 4096; i += 256) lw1[i] = w1f[i];
  for (int i = t; i < 2048; i += 256) lwk[i] = wkt[i];
  if (t < 32) lbf[t] = bfp[t];
  __syncthreads();

  int b  = blockIdx.y;
  int px = blockIdx.x * 256 + t;
  const float* xb = x + (size_t)b * 128 * NPIX;

  float acc[48];
#pragma unroll
  for (int i = 0; i < 48; ++i) acc[i] = 0.f;

  for (int c = 0; c < 128; ++c) {
    float xv = xb[(size_t)c * NPIX + px];
    const float4* w1p = (const float4*)(lw1 + c * 32);
#pragma unroll
    for (int j = 0; j < 8; ++j) {
      float4 w = w1p[j];
      acc[j*4+0] = fmaf(w.x, xv, acc[j*4+0]);
      acc[j*4+1] = fmaf(w.y, xv, acc[j*4+1]);
      acc[j*4+2] = fmaf(w.z, xv, acc[j*4+2]);
      acc[j*4+3] = fmaf(w.w, xv, acc[j*4+3]);
    }
    const float4* wkp = (const float4*)(lwk + c * 16);
#pragma unroll
    for (int j = 0; j < 4; ++j) {
      float4 w = wkp[j];
      acc[32+j*4+0] = fmaf(w.x, xv, acc[32+j*4+0]);
      acc[32+j*4+1] = fmaf(w.y, xv, acc[32+j*4+1]);
      acc[32+j*4+2] = fmaf(w.z, xv, acc[32+j*4+2]);
      acc[32+j*4+3] = fmaf(w.w, xv, acc[32+j*4+3]);
    }
  }
#pragma unroll
  for (int o = 0; o < 32; ++o)
    out[((size_t)(b * 128 + o)) * NPIX + px] = fmaxf(acc[o] + lbf[o], 0.f);
#pragma unroll
  for (int m = 0; m < 16; ++m)
    Kbuf[((size_t)(b * 16 + m)) * NPIX + px] = acc[32 + m] + bk[m];
}

// ---------------- a2m: dilated 3x3 branches via bf16 MFMA, batch->XCD swizzled ----------------
__global__ __launch_bounds__(256) void a2m_kernel(const unsigned short* __restrict__ xt,
                                                  const unsigned short* __restrict__ wbt,
                                                  const float* __restrict__ bfp,
                                                  const unsigned short* __restrict__ zb,
                                                  float* __restrict__ out) {
  int t    = threadIdx.x;
  int wave = t >> 6, lane = t & 63;
  int l15  = lane & 15, cg = lane >> 4;
  // batch = idx & 7 -> XCD k (round-robin) works only on batch k: xt[b] = 4 MB = L2
  int idx  = blockIdx.x;
  int b    = idx & 7;
  int rest = idx >> 3;        // 0..191
  int hx   = rest & 63;       // h-tile
  int br   = rest >> 6;       // 0..2
  int d    = 6 * (br + 1);
  int h    = hx * 2 + (wave >> 1);
  int n0   = (wave & 1) * 64;
  const unsigned short* xb = xt + (size_t)b * NPIX * 128;
  const unsigned short* wb = wbt + (size_t)br * 9 * 32 * 128;

  f32x4 acc[2][4];
#pragma unroll
  for (int i = 0; i < 2; ++i)
#pragma unroll
    for (int j = 0; j < 4; ++j) acc[i][j] = (f32x4){0.f, 0.f, 0.f, 0.f};

  for (int cc = 0; cc < 4; ++cc) {
    int c0 = cc * 32 + cg * 8;
#pragma unroll
    for (int kh = 0; kh < 3; ++kh) {
      int srow = h + (kh - 1) * d;
      if ((unsigned)srow >= 128u) continue;          // wave-uniform skip
      const unsigned short* xr = xb + ((size_t)srow * 128) * 128 + c0;
#pragma unroll
      for (int kw = 0; kw < 3; ++kw) {
        int tap = kh * 3 + kw;
        const unsigned short* wt = wb + (size_t)(tap * 32) * 128 + c0;
        bf16x8 a0 = *(const bf16x8*)(wt + (size_t)l15 * 128);
        bf16x8 a1 = *(const bf16x8*)(wt + (size_t)(l15 + 16) * 128);
        int colbase = n0 + l15 + (kw - 1) * d;
#pragma unroll
        for (int nf = 0; nf < 4; ++nf) {
          int col = colbase + nf * 16;
          const unsigned short* sp =
              ((unsigned)col < 128u) ? (xr + (size_t)col * 128) : zb;
          bf16x8 bv = *(const bf16x8*)sp;
          acc[0][nf] = __builtin_amdgcn_mfma_f32_16x16x32_bf16(a0, bv, acc[0][nf], 0, 0, 0);
          acc[1][nf] = __builtin_amdgcn_mfma_f32_16x16x32_bf16(a1, bv, acc[1][nf], 0, 0, 0);
        }
      }
    }
  }

  int ocb = (br + 1) * 32;
  int pxw = hx * 256 + (wave >> 1) * 128 + n0;
#pragma unroll
  for (int mf = 0; mf < 2; ++mf) {
#pragma unroll
    for (int r = 0; r < 4; ++r) {
      int oc = mf * 16 + cg * 4 + r;
      float bias = bfp[ocb + oc];
      float* op = out + ((size_t)(b * 128 + ocb + oc)) * NPIX + pxw + l15;
#pragma unroll
      for (int nf = 0; nf < 4; ++nf)
        op[nf * 16] = fmaxf(acc[mf][nf][r] + bias, 0.f);
    }
  }
}

// ---------------- a2f: fp32 fallback dilated conv ----------------
__global__ __launch_bounds__(256) void a2f_kernel(const float* __restrict__ x,
                                                  const float* __restrict__ w24t,
                                                  const float* __restrict__ bfp,
                                                  float* __restrict__ out) {
  int t  = threadIdx.x;
  int og = t & 3;
  int pg = (t >> 2) & 15;
  int r  = t >> 6;
  int br = blockIdx.z;
  int b  = blockIdx.y;
  int h  = blockIdx.x * 4 + r;
  int d  = 6 * (br + 1);

  const float* wt = w24t + (size_t)br * 36864;
  const float* bf = bfp + (br + 1) * 32;
  const float* xb = x + (size_t)b * 128 * NPIX;
  int w0 = pg << 3;

  float acc[8][8];
#pragma unroll
  for (int p = 0; p < 8; ++p)
#pragma unroll
    for (int o = 0; o < 8; ++o) acc[p][o] = 0.f;

  for (int c = 0; c < 128; ++c) {
    const float* xc = xb + (size_t)c * NPIX;
    const float* wc = wt + c * 288;
#pragma unroll
    for (int kh = 0; kh < 3; ++kh) {
      int row = h + (kh - 1) * d;
      if ((unsigned)row >= 128u) continue;
      const float* xr = xc + row * 128;
#pragma unroll
      for (int kw = 0; kw < 3; ++kw) {
        int wb = w0 + (kw - 1) * d;
        float xv[8];
        if (wb >= 0 && wb <= 120) {
          const float2* p2 = (const float2*)(xr + wb);
#pragma unroll
          for (int j = 0; j < 4; ++j) {
            float2 v = p2[j];
            xv[2*j] = v.x; xv[2*j+1] = v.y;
          }
        } else {
#pragma unroll
          for (int j = 0; j < 8; ++j) {
            int ww = wb + j;
            xv[j] = ((unsigned)ww < 128u) ? xr[ww] : 0.f;
          }
        }
        const float4* wp = (const float4*)(wc + (kh * 3 + kw) * 32 + og * 8);
        float4 wa = wp[0], wbv = wp[1];
        float wr[8] = {wa.x, wa.y, wa.z, wa.w, wbv.x, wbv.y, wbv.z, wbv.w};
#pragma unroll
        for (int p = 0; p < 8; ++p)
#pragma unroll
          for (int o = 0; o < 8; ++o)
            acc[p][o] = fmaf(xv[p], wr[o], acc[p][o]);
      }
    }
  }

  int chbase = (br + 1) * 32 + og * 8;
  int n = h * 128 + w0;
#pragma unroll
  for (int o = 0; o < 8; ++o) {
    float bias = bf[og * 8 + o];
    float* op = out + ((size_t)(b * 128 + chbase + o)) * NPIX + n;
    float4 v0 = make_float4(fmaxf(acc[0][o] + bias, 0.f), fmaxf(acc[1][o] + bias, 0.f),
                            fmaxf(acc[2][o] + bias, 0.f), fmaxf(acc[3][o] + bias, 0.f));
    float4 v1 = make_float4(fmaxf(acc[4][o] + bias, 0.f), fmaxf(acc[5][o] + bias, 0.f),
                            fmaxf(acc[6][o] + bias, 0.f), fmaxf(acc[7][o] + bias, 0.f));
    ((float4*)op)[0] = v0;
    ((float4*)op)[1] = v1;
  }
}

// ---------------- cm: V via bf16 MFMA on xt, Kn, accumulate mat/vsum/ksum partials ----------------
__global__ __launch_bounds__(256) void cm_kernel(const unsigned short* __restrict__ xt,
                                                 const unsigned short* __restrict__ wvb,
                                                 const float* __restrict__ bv,
                                                 const float* __restrict__ Kbuf,
                                                 float* __restrict__ part) {
  __shared__ float Vl[128 * 129];   // [oc][px] stride 129
  __shared__ float knl[16 * 132];   // [m][px] stride 132
  int t    = threadIdx.x;
  int b    = blockIdx.y;
  int blk  = blockIdx.x;
  int wave = t >> 6, lane = t & 63;
  int l15  = lane & 15, cg = lane >> 4;
  int ocb  = wave * 32;
  const float* Kb = Kbuf + (size_t)b * 16 * NPIX;
  const unsigned short* xb = xt + (size_t)b * NPIX * 128;

  int m_own = t & 15;
  int c0    = (t >> 4) << 3;   // phase-3 mat column block

  float bvr[2][4];
#pragma unroll
  for (int mf = 0; mf < 2; ++mf)
#pragma unroll
    for (int r = 0; r < 4; ++r) bvr[mf][r] = bv[ocb + mf * 16 + cg * 4 + r];

  float macc[8] = {0,0,0,0,0,0,0,0};
  float vs[8]   = {0,0,0,0,0,0,0,0};
  float ksum[16];
#pragma unroll
  for (int m = 0; m < 16; ++m) ksum[m] = 0.f;

  for (int tile = blk; tile < 128; tile += 64) {
    __syncthreads();   // previous tile's phase-3 reads done before overwriting LDS
    int pbase = tile << 7;

    // phase 1: Kn for this tile (threads 0..127, one pixel each)
    if (t < 128) {
      float kv[16]; float ss = 0.f;
#pragma unroll
      for (int m = 0; m < 16; ++m) {
        kv[m] = Kb[(size_t)m * NPIX + pbase + t];
        ss = fmaf(kv[m], kv[m], ss);
      }
      float inv = rsqrtf(ss);
#pragma unroll
      for (int m = 0; m < 16; ++m) {
        float kn = kv[m] * inv;
        knl[m * 132 + t] = kn;
        ksum[m] += kn;
      }
    }

    // phase 2: V[128oc][128px] = wv @ xt^T via MFMA; wave owns 32 oc rows
    f32x4 acc[2][8];
#pragma unroll
    for (int i = 0; i < 2; ++i)
#pragma unroll
      for (int j = 0; j < 8; ++j) acc[i][j] = (f32x4){0.f, 0.f, 0.f, 0.f};
#pragma unroll
    for (int cc = 0; cc < 4; ++cc) {
      int cbase = cc * 32 + cg * 8;
      bf16x8 a0 = *(const bf16x8*)(wvb + (size_t)(ocb + l15) * 128 + cbase);
      bf16x8 a1 = *(const bf16x8*)(wvb + (size_t)(ocb + 16 + l15) * 128 + cbase);
#pragma unroll
      for (int nf = 0; nf < 8; ++nf) {
        bf16x8 bvv = *(const bf16x8*)(xb + (size_t)(pbase + nf * 16 + l15) * 128 + cbase);
        acc[0][nf] = __builtin_amdgcn_mfma_f32_16x16x32_bf16(a0, bvv, acc[0][nf], 0, 0, 0);
        acc[1][nf] = __builtin_amdgcn_mfma_f32_16x16x32_bf16(a1, bvv, acc[1][nf], 0, 0, 0);
      }
    }
#pragma unroll
    for (int mf = 0; mf < 2; ++mf)
#pragma unroll
      for (int nf = 0; nf < 8; ++nf)
#pragma unroll
        for (int r = 0; r < 4; ++r)
          Vl[(size_t)(ocb + mf * 16 + cg * 4 + r) * 129 + nf * 16 + l15] =
              acc[mf][nf][r] + bvr[mf][r];
    __syncthreads();

    // phase 3: mat[m][c] += kn[m][px] * V[c][px]; vsum
    for (int px = 0; px < 128; ++px) {
      float knv = knl[m_own * 132 + px];
      float vv[8];
#pragma unroll
      for (int j = 0; j < 8; ++j) vv[j] = Vl[(c0 + j) * 129 + px];
#pragma unroll
      for (int j = 0; j < 8; ++j) macc[j] = fmaf(knv, vv[j], macc[j]);
      if (m_own == 0) {
#pragma unroll
        for (int j = 0; j < 8; ++j) vs[j] += vv[j];
      }
    }
  }

  // write partials
  int blkid = b * 64 + blk;
  float* pp = part + (size_t)blkid * 2192;
#pragma unroll
  for (int j = 0; j < 8; ++j) pp[m_own * 128 + c0 + j] = macc[j];
  if (m_own == 0) {
#pragma unroll
    for (int j = 0; j < 8; ++j) pp[2048 + c0 + j] = vs[j];
  }
  __syncthreads();
  if (t < 128) {
#pragma unroll
    for (int m = 0; m < 16; ++m) knl[m * 132 + t] = ksum[m];
  }
  __syncthreads();
  if (t < 16) {
    float s = 0.f;
    for (int i = 0; i < 128; ++i) s += knl[t * 132 + i];
    pp[2048 + 128 + t] = s;
  }
}

// ---------------- cf: fp32 fallback c-kernel ----------------
__global__ __launch_bounds__(256) void cf_kernel(const float* __restrict__ x,
                                                 const float* __restrict__ bv,
                                                 const float* __restrict__ Kbuf,
                                                 const float* __restrict__ wvt,
                                                 float* __restrict__ part) {
  __shared__ float Vl[128 * 129];
  __shared__ float knl[16 * 132];
  int t   = threadIdx.x;
  int b   = blockIdx.y;
  int blk = blockIdx.x;
  const float* Kb = Kbuf + (size_t)b * 16 * NPIX;
  const float* xb = x + (size_t)b * 128 * NPIX;

  int m_own = t & 15;
  int c0    = (t >> 4) << 3;
  int pxg   = t & 15;

  float bvr[8];
#pragma unroll
  for (int j = 0; j < 8; ++j) bvr[j] = bv[c0 + j];

  float macc[8] = {0,0,0,0,0,0,0,0};
  float vs[8]   = {0,0,0,0,0,0,0,0};
  float ksum[16];
#pragma unroll
  for (int m = 0; m < 16; ++m) ksum[m] = 0.f;

  for (int tile = blk; tile < 128; tile += 64) {
    __syncthreads();
    int pbase = tile << 7;

    if (t < 128) {
      float kv[16]; float ss = 0.f;
#pragma unroll
      for (int m = 0; m < 16; ++m) {
        kv[m] = Kb[(size_t)m * NPIX + pbase + t];
        ss = fmaf(kv[m], kv[m], ss);
      }
      float inv = rsqrtf(ss);
#pragma unroll
      for (int m = 0; m < 16; ++m) {
        float kn = kv[m] * inv;
        knl[m * 132 + t] = kn;
        ksum[m] += kn;
      }
    }

    float v[8][8];
#pragma unroll
    for (int i = 0; i < 8; ++i)
#pragma unroll
      for (int j = 0; j < 8; ++j) v[i][j] = 0.f;
    int px0 = pbase + (pxg << 3);
    for (int k = 0; k < 128; ++k) {
      const float4* xp = (const float4*)(xb + (size_t)k * NPIX + px0);
      float4 xa = xp[0], xc4 = xp[1];
      const float4* wp = (const float4*)(wvt + k * 128 + c0);
      float4 wa = wp[0], wc4 = wp[1];
      float xv[8] = {xa.x, xa.y, xa.z, xa.w, xc4.x, xc4.y, xc4.z, xc4.w};
      float wr[8] = {wa.x, wa.y, wa.z, wa.w, wc4.x, wc4.y, wc4.z, wc4.w};
#pragma unroll
      for (int i = 0; i < 8; ++i)
#pragma unroll
        for (int j = 0; j < 8; ++j)
          v[i][j] = fmaf(wr[i], xv[j], v[i][j]);
    }
#pragma unroll
    for (int i = 0; i < 8; ++i)
#pragma unroll
      for (int j = 0; j < 8; ++j)
        Vl[(c0 + i) * 129 + (pxg << 3) + j] = v[i][j] + bvr[i];
    __syncthreads();

    for (int px = 0; px < 128; ++px) {
      float knv = knl[m_own * 132 + px];
      float vv[8];
#pragma unroll
      for (int j = 0; j < 8; ++j) vv[j] = Vl[(c0 + j) * 129 + px];
#pragma unroll
      for (int j = 0; j < 8; ++j) macc[j] = fmaf(knv, vv[j], macc[j]);
      if (m_own == 0) {
#pragma unroll
        for (int j = 0; j < 8; ++j) vs[j] += vv[j];
      }
    }
  }

  int blkid = b * 64 + blk;
  float* pp = part + (size_t)blkid * 2192;
#pragma unroll
  for (int j = 0; j < 8; ++j) pp[m_own * 128 + c0 + j] = macc[j];
  if (m_own == 0) {
#pragma unroll
    for (int j = 0; j < 8; ++j) pp[2048 + c0 + j] = vs[j];
  }
  __syncthreads();
  if (t < 128) {
#pragma unroll
    for (int m = 0; m < 16; ++m) knl[m * 132 + t] = ksum[m];
  }
  __syncthreads();
  if (t < 16) {
    float s = 0.f;
    for (int i = 0; i < 128; ++i) s += knl[t * 132 + i];
    pp[2048 + 128 + t] = s;
  }
}

// ---------------- reduce partials -> stats ----------------
__global__ void reduce_kernel(const float* __restrict__ part, float* __restrict__ stats) {
  int b = blockIdx.x, t = threadIdx.x;
  const float* pp = part + (size_t)b * 64 * 2192;
  float* st = stats + (size_t)b * 2192;
  for (int e = t; e < 2192; e += 256) {
    float s = 0.f;
    for (int g = 0; g < 64; ++g) s += pp[(size_t)g * 2192 + e];
    st[e] = s;
  }
}

// ---------------- d: Q from x_q (in d_out), tailor, final output ----------------
__global__ __launch_bounds__(256) void d_kernel(const float* __restrict__ stats,
                                                const float* __restrict__ wq,
                                                const float* __restrict__ bq,
                                                const float* __restrict__ gamma,
                                                float* __restrict__ out) {
  __shared__ float matl[128 * 16];
  __shared__ float wql[128 * 16];
  __shared__ float vsl[128];
  __shared__ float ksl[16];
  int t = threadIdx.x;
  int b = blockIdx.y;
  const float* st = stats + (size_t)b * 2192;
  for (int i = t; i < 2048; i += 256) {
    int m = i >> 7, c = i & 127;
    matl[c * 16 + m] = st[i];
    wql[c * 16 + m]  = wq[m * 128 + c];
  }
  if (t < 128) vsl[t] = st[2048 + t];
  if (t < 16)  ksl[t] = st[2048 + 128 + t] + EPS_V;
  __syncthreads();

  int px = blockIdx.x * 256 + t;
  float* ob = out + (size_t)b * 128 * NPIX;

  float q[16];
#pragma unroll
  for (int m = 0; m < 16; ++m) q[m] = bq[m];
  for (int c = 0; c < 128; ++c) {
    float xv = ob[(size_t)c * NPIX + px];
    const float4* wp = (const float4*)(wql + c * 16);
#pragma unroll
    for (int j = 0; j < 4; ++j) {
      float4 w = wp[j];
      q[j*4+0] = fmaf(w.x, xv, q[j*4+0]);
      q[j*4+1] = fmaf(w.y, xv, q[j*4+1]);
      q[j*4+2] = fmaf(w.z, xv, q[j*4+2]);
      q[j*4+3] = fmaf(w.w, xv, q[j*4+3]);
    }
  }
  float ss = 0.f;
#pragma unroll
  for (int m = 0; m < 16; ++m) ss = fmaf(q[m], q[m], ss);
  float inv = rsqrtf(ss);
#pragma unroll
  for (int m = 0; m < 16; ++m) q[m] *= inv;
  float den = (float)NPIX;
#pragma unroll
  for (int m = 0; m < 16; ++m) den = fmaf(q[m], ksl[m], den);
  float tl = gamma[0] / den;

  for (int c = 0; c < 128; ++c) {
    float s = vsl[c];
    const float4* mp = (const float4*)(matl + c * 16);
#pragma unroll
    for (int j = 0; j < 4; ++j) {
      float4 w = mp[j];
      s = fmaf(w.x, q[j*4+0], s);
      s = fmaf(w.y, q[j*4+1], s);
      s = fmaf(w.z, q[j*4+2], s);
      s = fmaf(w.w, q[j*4+3], s);
    }
    ob[(size_t)c * NPIX + px] = tl * s;
  }
}

extern "C" void kernel_launch(void* const* d_in, const int* in_sizes, int n_in,
                              void* d_out, int out_size, void* d_ws, size_t ws_size,
                              hipStream_t stream) {
  (void)in_sizes; (void)n_in; (void)out_size;
  const float* x   = (const float*)d_in[0];
  const float* w1  = (const float*)d_in[1];
  const float* w2  = (const float*)d_in[2];
  const float* w3  = (const float*)d_in[3];
  const float* w4  = (const float*)d_in[4];
  const float* bns = (const float*)d_in[5];
  const float* bnb = (const float*)d_in[6];
  const float* bnm = (const float*)d_in[7];
  const float* bnv = (const float*)d_in[8];
  const float* wq  = (const float*)d_in[9];
  const float* bq  = (const float*)d_in[10];
  const float* wk  = (const float*)d_in[11];
  const float* bk  = (const float*)d_in[12];
  const float* wv  = (const float*)d_in[13];
  const float* bv  = (const float*)d_in[14];
  const float* gm  = (const float*)d_in[15];
  float* ws  = (float*)d_ws;
  float* out = (float*)d_out;

  float* Kbuf = ws + OFF_K;
  float* w1f  = ws + OFF_W1F;
  float* wkt  = ws + OFF_WKT;
  float* wvt  = ws + OFF_WVT;
  float* bfp  = ws + OFF_BF;
  float* part = ws + OFF_PART;
  float* stat = ws + OFF_STATS;

  prep_common_kernel<<<64, 256, 0, stream>>>(w1, bns, bnb, bnm, bnv, wk, wv,
                                             w1f, wkt, wvt, bfp);

  bool use_mfma = ws_size >= NEW_END * sizeof(float);
  if (use_mfma) {
    unsigned short* wbt = (unsigned short*)(ws + OFF_WBT);
    float*          zb  = ws + OFF_ZB;
    unsigned short* xt  = (unsigned short*)(ws + OFF_XT);
    unsigned short* wvb = (unsigned short*)(ws + OFF_WVB);
    prep_convb_kernel<<<64, 256, 0, stream>>>(w2, w3, w4, bns, bnv, wv, wbt, zb, wvb);
    a0_kernel<<<dim3(256, 8), 256, 0, stream>>>(x, xt);
    a1_kernel<<<dim3(64, 8), 256, 0, stream>>>(x, w1f, wkt, bfp, bk, out, Kbuf);
    a2m_kernel<<<dim3(1536), 256, 0, stream>>>(xt, wbt, bfp,
                                               (const unsigned short*)zb, out);
    cm_kernel<<<dim3(64, 8), 256, 0, stream>>>(xt, wvb, bv, Kbuf, part);
  } else {
    float* w24t = ws + OFF_W24T;
    prep_convf_kernel<<<64, 256, 0, stream>>>(w2, w3, w4, bns, bnv, w24t);
    a1_kernel<<<dim3(64, 8), 256, 0, stream>>>(x, w1f, wkt, bfp, bk, out, Kbuf);
    a2f_kernel<<<dim3(32, 8, 3), 256, 0, stream>>>(x, w24t, bfp, out);
    cf_kernel<<<dim3(64, 8), 256, 0, stream>>>(x, bv, Kbuf, wvt, part);
  }
  reduce_kernel<<<8, 256, 0, stream>>>(part, stat);
  d_kernel<<<dim3(64, 8), 256, 0, stream>>>(stat, wq, bq, gm, out);
}

// Round 4
// 182.573 us; speedup vs baseline: 6.3233x; 1.7055x over previous
//
#include <hip/hip_runtime.h>
#include <hip/hip_bf16.h>
#include <math.h>

#define NPIX   16384
#define BATCH  8
#define BN_EPS 1e-5f
#define EPS_V  1e-6f

typedef __attribute__((ext_vector_type(8))) short bf16x8;
typedef __attribute__((ext_vector_type(4))) float f32x4;

// ---- workspace layout (float offsets) ----
// common
#define OFF_K     ((size_t)0)          // 8*16*N   = 2097152
#define OFF_W1F   ((size_t)2097152)    // 128*32   = 4096
#define OFF_WKT   ((size_t)2101248)    // 128*16   = 2048
#define OFF_WVT   ((size_t)2103296)    // 128*128  = 16384
#define OFF_BF    ((size_t)2119680)    // 4*32     = 128
#define OFF_PART  ((size_t)2119808)    // 512*2192 = 1122304
#define OFF_STATS ((size_t)3242112)    // 8*2192   = 17536
#define BASE_END  ((size_t)3259648)
// new (bf16-MFMA) path extras
#define OFF_WBT   BASE_END             // 3*9*4*2*64*8 ushort = 55296 floats
#define OFF_ZB    ((size_t)3314944)    // 32 floats (unused, layout keep)
#define OFF_XT    ((size_t)3314976)    // 8*4*16384*32 ushort = 8388608 floats
#define OFF_WVB   ((size_t)11703584)   // 4*8*64*8 ushort = 8192 floats
#define NEW_END   ((size_t)11711776)
// old (fp32) fallback extras
#define OFF_W24T  BASE_END             // 3*128*9*32 = 110592
#define OLD_END   ((size_t)3370240)

__device__ inline unsigned short f2bf(float f) {
  union { float f; unsigned int u; } v; v.f = f;
  unsigned int r = (v.u + 0x7FFFu + ((v.u >> 16) & 1u)) >> 16;
  return (unsigned short)r;
}

// ---------------- prep_common: BN-folded 1x1 weights, K/V weights, biases ----------------
__global__ void prep_common_kernel(const float* __restrict__ w1,
                                   const float* __restrict__ bns, const float* __restrict__ bnb,
                                   const float* __restrict__ bnm, const float* __restrict__ bnv,
                                   const float* __restrict__ wk, const float* __restrict__ wv,
                                   float* __restrict__ w1f, float* __restrict__ wkt,
                                   float* __restrict__ wvt, float* __restrict__ bf) {
  int tid = blockIdx.x * blockDim.x + threadIdx.x;
  int nt  = gridDim.x * blockDim.x;
  for (int i = tid; i < 128; i += nt) {
    float inv = bns[i] * rsqrtf(bnv[i] + BN_EPS);
    bf[i] = bnb[i] - bnm[i] * inv;
  }
  for (int i = tid; i < 4096; i += nt) {          // w1f[c][o]
    int c = i >> 5, o = i & 31;
    float inv = bns[o] * rsqrtf(bnv[o] + BN_EPS);
    w1f[i] = w1[o * 128 + c] * inv;
  }
  for (int i = tid; i < 2048; i += nt) {          // wkt[c][m]
    int c = i >> 4, m = i & 15;
    wkt[i] = wk[m * 128 + c];
  }
  for (int i = tid; i < 16384; i += nt) {         // wvt[c][o]
    int c = i >> 7, o = i & 127;
    wvt[i] = wv[o * 128 + c];
  }
}

// ---------------- prep_convb: MFMA-fragment-ordered bf16 weights ----------------
// wbtr[br][tap][q][pair][lane(64)][e(8)] : element = W[oc=pair*16+(lane&15)][c=q*32+(lane>>4)*8+e]
// wvbr[q][f(8)][lane(64)][e(8)]          : element = WV[oc=f*16+(lane&15)][c=q*32+(lane>>4)*8+e]
__global__ void prep_convb_kernel(const float* __restrict__ w2, const float* __restrict__ w3,
                                  const float* __restrict__ w4,
                                  const float* __restrict__ bns, const float* __restrict__ bnv,
                                  const float* __restrict__ wv,
                                  unsigned short* __restrict__ wbtr,
                                  unsigned short* __restrict__ wvbr) {
  int tid = blockIdx.x * blockDim.x + threadIdx.x;
  int nt  = gridDim.x * blockDim.x;
  for (int i = tid; i < 16384; i += nt) {
    int e = i & 7, lane = (i >> 3) & 63, f = (i >> 9) & 7, q = i >> 12;
    int oc = f * 16 + (lane & 15);
    int c  = q * 32 + (lane >> 4) * 8 + e;
    wvbr[i] = f2bf(wv[oc * 128 + c]);
  }
  for (int i = tid; i < 110592; i += nt) {
    int br = i / 36864;
    int r  = i - br * 36864;
    int tap  = r >> 12;
    int r2   = r & 4095;
    int q    = r2 >> 10;
    int r3   = r2 & 1023;
    int pair = r3 >> 9;
    int r4   = r3 & 511;
    int lane = r4 >> 3, e = r4 & 7;
    int oc = pair * 16 + (lane & 15);
    int c  = q * 32 + (lane >> 4) * 8 + e;
    const float* w = (br == 0) ? w2 : ((br == 1) ? w3 : w4);
    int bo = (br + 1) * 32 + oc;
    float inv = bns[bo] * rsqrtf(bnv[bo] + BN_EPS);
    wbtr[i] = f2bf(w[(oc * 128 + c) * 9 + tap] * inv);
  }
}

// ---------------- prep_convf: fp32 conv weights (fallback) [br][c][tap][o] ----------------
__global__ void prep_convf_kernel(const float* __restrict__ w2, const float* __restrict__ w3,
                                  const float* __restrict__ w4,
                                  const float* __restrict__ bns, const float* __restrict__ bnv,
                                  float* __restrict__ w24t) {
  int tid = blockIdx.x * blockDim.x + threadIdx.x;
  int nt  = gridDim.x * blockDim.x;
  for (int i = tid; i < 110592; i += nt) {
    int br  = i / 36864;
    int rem = i - br * 36864;
    int c   = rem / 288;
    int k   = (rem % 288) >> 5;
    int o   = rem & 31;
    const float* w = (br == 0) ? w2 : ((br == 1) ? w3 : w4);
    int bo = (br + 1) * 32 + o;
    float inv = bns[bo] * rsqrtf(bnv[bo] + BN_EPS);
    w24t[i] = w[(o * 128 + c) * 9 + k] * inv;
  }
}

// ---------------- a0: transpose x -> xt bf16, quarter-major [b][q][px][32c] ----------------
__global__ __launch_bounds__(256) void a0_kernel(const float* __restrict__ x,
                                                 unsigned short* __restrict__ xt) {
  __shared__ unsigned short Ts[64][132];
  int t   = threadIdx.x;
  int b   = blockIdx.y;
  int px0 = blockIdx.x * 64;
  const float* xb = x + (size_t)b * 128 * NPIX;
  int p = t & 63, cq = t >> 6;
#pragma unroll 8
  for (int i = 0; i < 32; ++i) {
    int c = cq * 32 + i;
    Ts[p][c] = f2bf(xb[(size_t)c * NPIX + px0 + p]);
  }
  __syncthreads();
  int pw = t >> 2, cg = t & 3;   // cg == quarter
  unsigned short* dst = xt + ((size_t)(b * 4 + cg) * 16384 + px0 + pw) * 32;
#pragma unroll
  for (int k = 0; k < 8; ++k) {
    uint2 v = *(const uint2*)(&Ts[pw][cg * 32 + k * 4]);
    *(uint2*)(dst + k * 4) = v;
  }
}

// ---------------- a1: 1x1 branch (bn+relu) -> out channels [0,32); K -> ws ----------------
__global__ __launch_bounds__(256) void a1_kernel(const float* __restrict__ x,
                                                 const float* __restrict__ w1f,
                                                 const float* __restrict__ wkt,
                                                 const float* __restrict__ bfp,
                                                 const float* __restrict__ bk,
                                                 float* __restrict__ out,
                                                 float* __restrict__ Kbuf) {
  __shared__ float lw1[128 * 32];
  __shared__ float lwk[128 * 16];
  __shared__ float lbf[32];
  int t = threadIdx.x;
  for (int i = t; i < 4096; i += 256) lw1[i] = w1f[i];
  for (int i = t; i < 2048; i += 256) lwk[i] = wkt[i];
  if (t < 32) lbf[t] = bfp[t];
  __syncthreads();

  int b  = blockIdx.y;
  int px = blockIdx.x * 256 + t;
  const float* xb = x + (size_t)b * 128 * NPIX;

  float acc[48];
#pragma unroll
  for (int i = 0; i < 48; ++i) acc[i] = 0.f;

  for (int c = 0; c < 128; ++c) {
    float xv = xb[(size_t)c * NPIX + px];
    const float4* w1p = (const float4*)(lw1 + c * 32);
#pragma unroll
    for (int j = 0; j < 8; ++j) {
      float4 w = w1p[j];
      acc[j*4+0] = fmaf(w.x, xv, acc[j*4+0]);
      acc[j*4+1] = fmaf(w.y, xv, acc[j*4+1]);
      acc[j*4+2] = fmaf(w.z, xv, acc[j*4+2]);
      acc[j*4+3] = fmaf(w.w, xv, acc[j*4+3]);
    }
    const float4* wkp = (const float4*)(lwk + c * 16);
#pragma unroll
    for (int j = 0; j < 4; ++j) {
      float4 w = wkp[j];
      acc[32+j*4+0] = fmaf(w.x, xv, acc[32+j*4+0]);
      acc[32+j*4+1] = fmaf(w.y, xv, acc[32+j*4+1]);
      acc[32+j*4+2] = fmaf(w.z, xv, acc[32+j*4+2]);
      acc[32+j*4+3] = fmaf(w.w, xv, acc[32+j*4+3]);
    }
  }
#pragma unroll
  for (int o = 0; o < 32; ++o)
    out[((size_t)(b * 128 + o)) * NPIX + px] = fmaxf(acc[o] + lbf[o], 0.f);
#pragma unroll
  for (int m = 0; m < 16; ++m)
    Kbuf[((size_t)(b * 16 + m)) * NPIX + px] = acc[32 + m] + bk[m];
}

// ---------------- a2m v3: dilated convs, LDS-staged rows + swizzle, MFMA ----------------
// block = (b, br, row-pair h0,h0+1); stage 6 input rows x 32c quarter (48KB) per q.
__global__ __launch_bounds__(256) void a2m_kernel(const unsigned short* __restrict__ xt,
                                                  const unsigned short* __restrict__ wbtr,
                                                  const float* __restrict__ bfp,
                                                  float* __restrict__ out) {
  __shared__ uint4 sxv[3073];                 // 48KB staged + 16B zero page
  unsigned short* sx = (unsigned short*)sxv;
  int t    = threadIdx.x;
  int wave = t >> 6, lane = t & 63;
  int l15  = lane & 15, cg = lane >> 4;
  int idx  = blockIdx.x;
  int b    = idx & 7;                         // batch -> XCD
  int rest = idx >> 3;
  int h2   = rest & 63;
  int br   = rest >> 6;
  int d    = 6 * (br + 1);
  int h0   = h2 * 2;
  int j    = wave >> 1;                       // which row of the pair
  int p0   = (wave & 1) * 64;                 // px half

  if (t == 0) sxv[3072] = make_uint4(0u, 0u, 0u, 0u);   // zero page @ byte 49152

  const unsigned short* wb = wbtr + (size_t)br * 36864;

  f32x4 acc[2][4];
#pragma unroll
  for (int i = 0; i < 2; ++i)
#pragma unroll
    for (int n = 0; n < 4; ++n) acc[i][n] = (f32x4){0.f, 0.f, 0.f, 0.f};

  int pxb[3], xorv[3];
#pragma unroll
  for (int kw = 0; kw < 3; ++kw) {
    pxb[kw]  = p0 + l15 + (kw - 1) * d;
    xorv[kw] = (cg ^ ((pxb[kw] >> 1) & 3)) << 4;   // valid for all nf (px+16 keeps bits)
  }

  for (int q = 0; q < 4; ++q) {
    __syncthreads();                            // previous compute done
    // ---- stage 6 rows x 8KB (reg-staged, coalesced reads, swizzled LDS writes) ----
    const unsigned short* slab = xt + (size_t)(b * 4 + q) * 524288;
    uint4 stv[12];
#pragma unroll
    for (int k = 0; k < 12; ++k) {
      int slot = k >> 1;                                  // kh*2 + jrow
      int srow = h0 + (slot & 1) + ((slot >> 1) - 1) * d;
      int su   = ((k & 1) << 8) + t;                      // 16B unit within slot
      if ((unsigned)srow < 128u)
        stv[k] = *(const uint4*)(slab + (size_t)srow * 4096 + su * 8);
      else
        stv[k] = make_uint4(0u, 0u, 0u, 0u);
    }
#pragma unroll
    for (int k = 0; k < 12; ++k) {
      int slot = k >> 1;
      int su   = ((k & 1) << 8) + t;
      int px   = su >> 2, cgs = su & 3;
      int phys = slot * 4096 + px * 32 + ((cgs ^ ((px >> 1) & 3)) << 3);  // ushort idx
      *(uint4*)(sx + phys) = stv[k];
    }
    __syncthreads();                            // staged visible
    // ---- compute: 9 taps x 32c ----
#pragma unroll
    for (int kh = 0; kh < 3; ++kh) {
      int slot  = kh * 2 + j;
      int sbase = slot * 8192;                  // byte
      bf16x8 a[3][2];
#pragma unroll
      for (int kw = 0; kw < 3; ++kw) {
        int tap = kh * 3 + kw;
        const unsigned short* wt = wb + ((((size_t)tap * 4 + q) * 2) << 9);
        a[kw][0] = *(const bf16x8*)(wt + lane * 8);
        a[kw][1] = *(const bf16x8*)(wt + 512 + lane * 8);
      }
#pragma unroll
      for (int kw = 0; kw < 3; ++kw) {
        int base = sbase + pxb[kw] * 64 + xorv[kw];
#pragma unroll
        for (int nf = 0; nf < 4; ++nf) {
          int px   = pxb[kw] + nf * 16;
          int addr = ((unsigned)px < 128u) ? (base + nf * 1024) : 49152;
          bf16x8 bv = *(const bf16x8*)((const char*)sx + addr);
          acc[0][nf] = __builtin_amdgcn_mfma_f32_16x16x32_bf16(a[kw][0], bv, acc[0][nf], 0, 0, 0);
          acc[1][nf] = __builtin_amdgcn_mfma_f32_16x16x32_bf16(a[kw][1], bv, acc[1][nf], 0, 0, 0);
        }
      }
    }
  }

  // epilogue: bias + relu, fp32 out
  int ocb = (br + 1) * 32;
  int pxw = (h0 + j) * 128 + p0;
#pragma unroll
  for (int mf = 0; mf < 2; ++mf) {
#pragma unroll
    for (int r = 0; r < 4; ++r) {
      int oc = mf * 16 + cg * 4 + r;
      float bias = bfp[ocb + oc];
      float* op = out + ((size_t)(b * 128 + ocb + oc)) * NPIX + pxw + l15;
#pragma unroll
      for (int nf = 0; nf < 4; ++nf)
        op[nf * 16] = fmaxf(acc[mf][nf][r] + bias, 0.f);
    }
  }
}

// ---------------- a2f: fp32 fallback dilated conv ----------------
__global__ __launch_bounds__(256) void a2f_kernel(const float* __restrict__ x,
                                                  const float* __restrict__ w24t,
                                                  const float* __restrict__ bfp,
                                                  float* __restrict__ out) {
  int t  = threadIdx.x;
  int og = t & 3;
  int pg = (t >> 2) & 15;
  int r  = t >> 6;
  int br = blockIdx.z;
  int b  = blockIdx.y;
  int h  = blockIdx.x * 4 + r;
  int d  = 6 * (br + 1);

  const float* wt = w24t + (size_t)br * 36864;
  const float* bf = bfp + (br + 1) * 32;
  const float* xb = x + (size_t)b * 128 * NPIX;
  int w0 = pg << 3;

  float acc[8][8];
#pragma unroll
  for (int p = 0; p < 8; ++p)
#pragma unroll
    for (int o = 0; o < 8; ++o) acc[p][o] = 0.f;

  for (int c = 0; c < 128; ++c) {
    const float* xc = xb + (size_t)c * NPIX;
    const float* wc = wt + c * 288;
#pragma unroll
    for (int kh = 0; kh < 3; ++kh) {
      int row = h + (kh - 1) * d;
      if ((unsigned)row >= 128u) continue;
      const float* xr = xc + row * 128;
#pragma unroll
      for (int kw = 0; kw < 3; ++kw) {
        int wb = w0 + (kw - 1) * d;
        float xv[8];
        if (wb >= 0 && wb <= 120) {
          const float2* p2 = (const float2*)(xr + wb);
#pragma unroll
          for (int jj = 0; jj < 4; ++jj) {
            float2 v = p2[jj];
            xv[2*jj] = v.x; xv[2*jj+1] = v.y;
          }
        } else {
#pragma unroll
          for (int jj = 0; jj < 8; ++jj) {
            int ww = wb + jj;
            xv[jj] = ((unsigned)ww < 128u) ? xr[ww] : 0.f;
          }
        }
        const float4* wp = (const float4*)(wc + (kh * 3 + kw) * 32 + og * 8);
        float4 wa = wp[0], wbv = wp[1];
        float wr[8] = {wa.x, wa.y, wa.z, wa.w, wbv.x, wbv.y, wbv.z, wbv.w};
#pragma unroll
        for (int p = 0; p < 8; ++p)
#pragma unroll
          for (int o = 0; o < 8; ++o)
            acc[p][o] = fmaf(xv[p], wr[o], acc[p][o]);
      }
    }
  }

  int chbase = (br + 1) * 32 + og * 8;
  int n = h * 128 + w0;
#pragma unroll
  for (int o = 0; o < 8; ++o) {
    float bias = bf[og * 8 + o];
    float* op = out + ((size_t)(b * 128 + chbase + o)) * NPIX + n;
    float4 v0 = make_float4(fmaxf(acc[0][o] + bias, 0.f), fmaxf(acc[1][o] + bias, 0.f),
                            fmaxf(acc[2][o] + bias, 0.f), fmaxf(acc[3][o] + bias, 0.f));
    float4 v1 = make_float4(fmaxf(acc[4][o] + bias, 0.f), fmaxf(acc[5][o] + bias, 0.f),
                            fmaxf(acc[6][o] + bias, 0.f), fmaxf(acc[7][o] + bias, 0.f));
    ((float4*)op)[0] = v0;
    ((float4*)op)[1] = v1;
  }
}

// ---------------- cm v3: V via MFMA; mat via MFMA on LDS bf16 Kn/V ----------------
__global__ __launch_bounds__(256) void cm_kernel(const unsigned short* __restrict__ xt,
                                                 const unsigned short* __restrict__ wvbr,
                                                 const float* __restrict__ bv,
                                                 const float* __restrict__ Kbuf,
                                                 float* __restrict__ part) {
  __shared__ __align__(16) unsigned short Vl[128 * 136];   // bf16 [oc][px], stride 136
  __shared__ __align__(16) unsigned short knl[16 * 136];   // bf16 [m][px]
  __shared__ float rbuf[16 * 128];                         // fp32 ksum reduce
  int t    = threadIdx.x;
  int b    = blockIdx.y;
  int blk  = blockIdx.x;
  int wave = t >> 6, lane = t & 63;
  int l15  = lane & 15, cg = lane >> 4;
  int ocb  = wave * 32;
  const float* Kb = Kbuf + (size_t)b * 16 * NPIX;

  float bvr[2][4];
#pragma unroll
  for (int mf = 0; mf < 2; ++mf)
#pragma unroll
    for (int r = 0; r < 4; ++r) bvr[mf][r] = bv[ocb + mf * 16 + cg * 4 + r];

  float ksum[16];
#pragma unroll
  for (int m = 0; m < 16; ++m) ksum[m] = 0.f;
  float sv[2][4];
#pragma unroll
  for (int mf = 0; mf < 2; ++mf)
#pragma unroll
    for (int r = 0; r < 4; ++r) sv[mf][r] = 0.f;
  f32x4 am[2];
  am[0] = (f32x4){0.f,0.f,0.f,0.f};
  am[1] = (f32x4){0.f,0.f,0.f,0.f};

  for (int tile = blk; tile < 128; tile += 64) {
    __syncthreads();   // prior phase-3 reads done before overwriting LDS
    int pbase = tile << 7;

    // phase 1: Kn (fp32 math, bf16 store), ksum fp32
    if (t < 128) {
      float kv[16]; float ss = 0.f;
#pragma unroll
      for (int m = 0; m < 16; ++m) {
        kv[m] = Kb[(size_t)m * NPIX + pbase + t];
        ss = fmaf(kv[m], kv[m], ss);
      }
      float inv = rsqrtf(ss);
#pragma unroll
      for (int m = 0; m < 16; ++m) {
        float kn = kv[m] * inv;
        knl[m * 136 + t] = f2bf(kn);
        ksum[m] += kn;
      }
    }

    // phase 2: V[128oc][128px] via MFMA from quarter-major xt
    f32x4 vacc[2][8];
#pragma unroll
    for (int i = 0; i < 2; ++i)
#pragma unroll
      for (int n = 0; n < 8; ++n) vacc[i][n] = (f32x4){0.f,0.f,0.f,0.f};
#pragma unroll
    for (int cc = 0; cc < 4; ++cc) {
      const unsigned short* xq = xt + ((size_t)(b * 4 + cc) * 16384 + pbase) * 32;
      bf16x8 a0 = *(const bf16x8*)(wvbr + ((cc * 8 + wave * 2 + 0) << 9) + lane * 8);
      bf16x8 a1 = *(const bf16x8*)(wvbr + ((cc * 8 + wave * 2 + 1) << 9) + lane * 8);
#pragma unroll
      for (int nf = 0; nf < 8; ++nf) {
        bf16x8 bx = *(const bf16x8*)(xq + (size_t)(nf * 16 + l15) * 32 + cg * 8);
        vacc[0][nf] = __builtin_amdgcn_mfma_f32_16x16x32_bf16(a0, bx, vacc[0][nf], 0, 0, 0);
        vacc[1][nf] = __builtin_amdgcn_mfma_f32_16x16x32_bf16(a1, bx, vacc[1][nf], 0, 0, 0);
      }
    }
    // vsum partial (fp32, pre-round) + Vl bf16 write (bias included)
#pragma unroll
    for (int mf = 0; mf < 2; ++mf) {
#pragma unroll
      for (int r = 0; r < 4; ++r) {
        float s = 0.f;
#pragma unroll
        for (int nf = 0; nf < 8; ++nf) s += vacc[mf][nf][r];
        sv[mf][r] += s;
        int c = ocb + mf * 16 + cg * 4 + r;
#pragma unroll
        for (int nf = 0; nf < 8; ++nf)
          Vl[c * 136 + nf * 16 + l15] = f2bf(vacc[mf][nf][r] + bvr[mf][r]);
      }
    }
    __syncthreads();

    // phase 3: mat[m][c] += Kn·V^T via MFMA (A=knl rows m, B=Vl rows c, K=px)
#pragma unroll
    for (int ks = 0; ks < 4; ++ks) {
      bf16x8 af = *(const bf16x8*)(knl + l15 * 136 + ks * 32 + cg * 8);
      bf16x8 b0 = *(const bf16x8*)(Vl + (size_t)(ocb + l15) * 136 + ks * 32 + cg * 8);
      bf16x8 b1 = *(const bf16x8*)(Vl + (size_t)(ocb + 16 + l15) * 136 + ks * 32 + cg * 8);
      am[0] = __builtin_amdgcn_mfma_f32_16x16x32_bf16(af, b0, am[0], 0, 0, 0);
      am[1] = __builtin_amdgcn_mfma_f32_16x16x32_bf16(af, b1, am[1], 0, 0, 0);
    }
  }

  // ---- write partials ----
  int blkid = b * 64 + blk;
  float* pp = part + (size_t)blkid * 2192;
  // mat: D row = m = cg*4+r, col = c = ocb + nf2*16 + l15
#pragma unroll
  for (int nf2 = 0; nf2 < 2; ++nf2)
#pragma unroll
    for (int r = 0; r < 4; ++r)
      pp[(cg * 4 + r) * 128 + ocb + nf2 * 16 + l15] = am[nf2][r];
  // vsum: reduce over l15 (16-lane groups)
#pragma unroll
  for (int off = 1; off < 16; off <<= 1) {
#pragma unroll
    for (int mf = 0; mf < 2; ++mf)
#pragma unroll
      for (int r = 0; r < 4; ++r)
        sv[mf][r] += __shfl_xor(sv[mf][r], off);
  }
  if (l15 == 0) {
#pragma unroll
    for (int mf = 0; mf < 2; ++mf)
#pragma unroll
      for (int r = 0; r < 4; ++r) {
        int c = ocb + mf * 16 + cg * 4 + r;
        pp[2048 + c] = sv[mf][r] + 256.f * bv[c];
      }
  }
  // ksum block-reduce
  __syncthreads();
  if (t < 128) {
#pragma unroll
    for (int m = 0; m < 16; ++m) rbuf[m * 128 + t] = ksum[m];
  }
  __syncthreads();
  if (t < 16) {
    float s = 0.f;
    for (int i = 0; i < 128; ++i) s += rbuf[t * 128 + i];
    pp[2048 + 128 + t] = s;
  }
}

// ---------------- cf: fp32 fallback c-kernel ----------------
__global__ __launch_bounds__(256) void cf_kernel(const float* __restrict__ x,
                                                 const float* __restrict__ bv,
                                                 const float* __restrict__ Kbuf,
                                                 const float* __restrict__ wvt,
                                                 float* __restrict__ part) {
  __shared__ float Vl[128 * 129];
  __shared__ float knl[16 * 132];
  int t   = threadIdx.x;
  int b   = blockIdx.y;
  int blk = blockIdx.x;
  const float* Kb = Kbuf + (size_t)b * 16 * NPIX;
  const float* xb = x + (size_t)b * 128 * NPIX;

  int m_own = t & 15;
  int c0    = (t >> 4) << 3;
  int pxg   = t & 15;

  float bvr[8];
#pragma unroll
  for (int jj = 0; jj < 8; ++jj) bvr[jj] = bv[c0 + jj];

  float macc[8] = {0,0,0,0,0,0,0,0};
  float vs[8]   = {0,0,0,0,0,0,0,0};
  float ksum[16];
#pragma unroll
  for (int m = 0; m < 16; ++m) ksum[m] = 0.f;

  for (int tile = blk; tile < 128; tile += 64) {
    __syncthreads();
    int pbase = tile << 7;

    if (t < 128) {
      float kv[16]; float ss = 0.f;
#pragma unroll
      for (int m = 0; m < 16; ++m) {
        kv[m] = Kb[(size_t)m * NPIX + pbase + t];
        ss = fmaf(kv[m], kv[m], ss);
      }
      float inv = rsqrtf(ss);
#pragma unroll
      for (int m = 0; m < 16; ++m) {
        float kn = kv[m] * inv;
        knl[m * 132 + t] = kn;
        ksum[m] += kn;
      }
    }

    float v[8][8];
#pragma unroll
    for (int i = 0; i < 8; ++i)
#pragma unroll
      for (int jj = 0; jj < 8; ++jj) v[i][jj] = 0.f;
    int px0 = pbase + (pxg << 3);
    for (int k = 0; k < 128; ++k) {
      const float4* xp = (const float4*)(xb + (size_t)k * NPIX + px0);
      float4 xa = xp[0], xc4 = xp[1];
      const float4* wp = (const float4*)(wvt + k * 128 + c0);
      float4 wa = wp[0], wc4 = wp[1];
      float xv[8] = {xa.x, xa.y, xa.z, xa.w, xc4.x, xc4.y, xc4.z, xc4.w};
      float wr[8] = {wa.x, wa.y, wa.z, wa.w, wc4.x, wc4.y, wc4.z, wc4.w};
#pragma unroll
      for (int i = 0; i < 8; ++i)
#pragma unroll
        for (int jj = 0; jj < 8; ++jj)
          v[i][jj] = fmaf(wr[i], xv[jj], v[i][jj]);
    }
#pragma unroll
    for (int i = 0; i < 8; ++i)
#pragma unroll
      for (int jj = 0; jj < 8; ++jj)
        Vl[(c0 + i) * 129 + (pxg << 3) + jj] = v[i][jj] + bvr[i];
    __syncthreads();

    for (int px = 0; px < 128; ++px) {
      float knv = knl[m_own * 132 + px];
      float vv[8];
#pragma unroll
      for (int jj = 0; jj < 8; ++jj) vv[jj] = Vl[(c0 + jj) * 129 + px];
#pragma unroll
      for (int jj = 0; jj < 8; ++jj) macc[jj] = fmaf(knv, vv[jj], macc[jj]);
      if (m_own == 0) {
#pragma unroll
        for (int jj = 0; jj < 8; ++jj) vs[jj] += vv[jj];
      }
    }
  }

  int blkid = b * 64 + blk;
  float* pp = part + (size_t)blkid * 2192;
#pragma unroll
  for (int jj = 0; jj < 8; ++jj) pp[m_own * 128 + c0 + jj] = macc[jj];
  if (m_own == 0) {
#pragma unroll
    for (int jj = 0; jj < 8; ++jj) pp[2048 + c0 + jj] = vs[jj];
  }
  __syncthreads();
  if (t < 128) {
#pragma unroll
    for (int m = 0; m < 16; ++m) knl[m * 132 + t] = ksum[m];
  }
  __syncthreads();
  if (t < 16) {
    float s = 0.f;
    for (int i = 0; i < 128; ++i) s += knl[t * 132 + i];
    pp[2048 + 128 + t] = s;
  }
}

// ---------------- reduce partials -> stats ----------------
__global__ void reduce_kernel(const float* __restrict__ part, float* __restrict__ stats) {
  int b = blockIdx.x, t = threadIdx.x;
  const float* pp = part + (size_t)b * 64 * 2192;
  float* st = stats + (size_t)b * 2192;
  for (int e = t; e < 2192; e += 256) {
    float s = 0.f;
    for (int g = 0; g < 64; ++g) s += pp[(size_t)g * 2192 + e];
    st[e] = s;
  }
}

// ---------------- d: Q from x_q (in d_out), tailor, final output ----------------
__global__ __launch_bounds__(256) void d_kernel(const float* __restrict__ stats,
                                                const float* __restrict__ wq,
                                                const float* __restrict__ bq,
                                                const float* __restrict__ gamma,
                                                float* __restrict__ out) {
  __shared__ float matl[128 * 16];
  __shared__ float wql[128 * 16];
  __shared__ float vsl[128];
  __shared__ float ksl[16];
  int t = threadIdx.x;
  int b = blockIdx.y;
  const float* st = stats + (size_t)b * 2192;
  for (int i = t; i < 2048; i += 256) {
    int m = i >> 7, c = i & 127;
    matl[c * 16 + m] = st[i];
    wql[c * 16 + m]  = wq[m * 128 + c];
  }
  if (t < 128) vsl[t] = st[2048 + t];
  if (t < 16)  ksl[t] = st[2048 + 128 + t] + EPS_V;
  __syncthreads();

  int px = blockIdx.x * 256 + t;
  float* ob = out + (size_t)b * 128 * NPIX;

  float q[16];
#pragma unroll
  for (int m = 0; m < 16; ++m) q[m] = bq[m];
  for (int c = 0; c < 128; ++c) {
    float xv = ob[(size_t)c * NPIX + px];
    const float4* wp = (const float4*)(wql + c * 16);
#pragma unroll
    for (int jj = 0; jj < 4; ++jj) {
      float4 w = wp[jj];
      q[jj*4+0] = fmaf(w.x, xv, q[jj*4+0]);
      q[jj*4+1] = fmaf(w.y, xv, q[jj*4+1]);
      q[jj*4+2] = fmaf(w.z, xv, q[jj*4+2]);
      q[jj*4+3] = fmaf(w.w, xv, q[jj*4+3]);
    }
  }
  float ss = 0.f;
#pragma unroll
  for (int m = 0; m < 16; ++m) ss = fmaf(q[m], q[m], ss);
  float inv = rsqrtf(ss);
#pragma unroll
  for (int m = 0; m < 16; ++m) q[m] *= inv;
  float den = (float)NPIX;
#pragma unroll
  for (int m = 0; m < 16; ++m) den = fmaf(q[m], ksl[m], den);
  float tl = gamma[0] / den;

  for (int c = 0; c < 128; ++c) {
    float s = vsl[c];
    const float4* mp = (const float4*)(matl + c * 16);
#pragma unroll
    for (int jj = 0; jj < 4; ++jj) {
      float4 w = mp[jj];
      s = fmaf(w.x, q[jj*4+0], s);
      s = fmaf(w.y, q[jj*4+1], s);
      s = fmaf(w.z, q[jj*4+2], s);
      s = fmaf(w.w, q[jj*4+3], s);
    }
    ob[(size_t)c * NPIX + px] = tl * s;
  }
}

extern "C" void kernel_launch(void* const* d_in, const int* in_sizes, int n_in,
                              void* d_out, int out_size, void* d_ws, size_t ws_size,
                              hipStream_t stream) {
  (void)in_sizes; (void)n_in; (void)out_size;
  const float* x   = (const float*)d_in[0];
  const float* w1  = (const float*)d_in[1];
  const float* w2  = (const float*)d_in[2];
  const float* w3  = (const float*)d_in[3];
  const float* w4  = (const float*)d_in[4];
  const float* bns = (const float*)d_in[5];
  const float* bnb = (const float*)d_in[6];
  const float* bnm = (const float*)d_in[7];
  const float* bnv = (const float*)d_in[8];
  const float* wq  = (const float*)d_in[9];
  const float* bq  = (const float*)d_in[10];
  const float* wk  = (const float*)d_in[11];
  const float* bk  = (const float*)d_in[12];
  const float* wv  = (const float*)d_in[13];
  const float* bv  = (const float*)d_in[14];
  const float* gm  = (const float*)d_in[15];
  float* ws  = (float*)d_ws;
  float* out = (float*)d_out;

  float* Kbuf = ws + OFF_K;
  float* w1f  = ws + OFF_W1F;
  float* wkt  = ws + OFF_WKT;
  float* wvt  = ws + OFF_WVT;
  float* bfp  = ws + OFF_BF;
  float* part = ws + OFF_PART;
  float* stat = ws + OFF_STATS;

  prep_common_kernel<<<64, 256, 0, stream>>>(w1, bns, bnb, bnm, bnv, wk, wv,
                                             w1f, wkt, wvt, bfp);

  bool use_mfma = ws_size >= NEW_END * sizeof(float);
  if (use_mfma) {
    unsigned short* wbtr = (unsigned short*)(ws + OFF_WBT);
    unsigned short* xt   = (unsigned short*)(ws + OFF_XT);
    unsigned short* wvbr = (unsigned short*)(ws + OFF_WVB);
    prep_convb_kernel<<<64, 256, 0, stream>>>(w2, w3, w4, bns, bnv, wv, wbtr, wvbr);
    a0_kernel<<<dim3(256, 8), 256, 0, stream>>>(x, xt);
    a1_kernel<<<dim3(64, 8), 256, 0, stream>>>(x, w1f, wkt, bfp, bk, out, Kbuf);
    a2m_kernel<<<dim3(1536), 256, 0, stream>>>(xt, wbtr, bfp, out);
    cm_kernel<<<dim3(64, 8), 256, 0, stream>>>(xt, wvbr, bv, Kbuf, part);
  } else {
    float* w24t = ws + OFF_W24T;
    prep_convf_kernel<<<64, 256, 0, stream>>>(w2, w3, w4, bns, bnv, w24t);
    a1_kernel<<<dim3(64, 8), 256, 0, stream>>>(x, w1f, wkt, bfp, bk, out, Kbuf);
    a2f_kernel<<<dim3(32, 8, 3), 256, 0, stream>>>(x, w24t, bfp, out);
    cf_kernel<<<dim3(64, 8), 256, 0, stream>>>(x, bv, Kbuf, wvt, part);
  }
  reduce_kernel<<<8, 256, 0, stream>>>(part, stat);
  d_kernel<<<dim3(64, 8), 256, 0, stream>>>(stat, wq, bq, gm, out);
}